// Round 2
// baseline (748.309 us; speedup 1.0000x reference)
//
#include <hip/hip_runtime.h>
#include <cmath>

// ---------------------------------------------------------------------------
// SpectralGAT: 2-layer GAT (H1=4,C1=128 concat -> 512; H=1,C2=64) + MLP(64->32
// ->LN->ReLU->16). f32 throughout. CSR built on device every call (no cached
// state), edge-index width (int32 vs int64) auto-detected on device.
// ---------------------------------------------------------------------------

#define F_IN 128
#define H1   4
#define C1   128
#define D1   512   // H1*C1
#define C2   64
#define DM1  32
#define DM2  16

#define LRELU(x) ((x) > 0.f ? (x) : 0.2f * (x))

// --------------------------- edge dtype detect ------------------------------
// int64 node ids < 2^31 => every odd 32-bit word is zero. For int32 data the
// odd words are arbitrary node ids (nonzero with overwhelming probability
// over 4096 samples spread across the array). flag=1 -> int64, flag=0 -> int32.
__global__ void k_detect(const void* ei, int E, int* flag) {
    __shared__ int any;
    if (threadIdx.x == 0) any = 0;
    __syncthreads();
    const int* p = (const int*)ei;
    int cnt = E < 4096 ? E : 4096;
    int stride = E / cnt;  // >= 1
    int local = 0;
    for (int i = threadIdx.x; i < cnt; i += blockDim.x) {
        long long idx = (long long)i * stride;
        local |= p[2 * idx + 1];
    }
    if (local) atomicOr(&any, 1);
    __syncthreads();
    if (threadIdx.x == 0) *flag = (any == 0) ? 1 : 0;
}

// Convert edge_index to int32 src/dst and append self-loops.
__global__ void k_convert(const void* ei, const int* flag, int E, int N,
                          int* src32, int* dst32) {
    int i = blockIdx.x * blockDim.x + threadIdx.x;
    int Etot = E + N;
    if (i >= Etot) return;
    if (i < E) {
        int s, d;
        if (*flag) {
            const long long* q = (const long long*)ei;
            s = (int)q[i];
            d = (int)q[(size_t)E + i];
        } else {
            const int* q = (const int*)ei;
            s = q[i];
            d = q[(size_t)E + i];
        }
        src32[i] = s;
        dst32[i] = d;
    } else {
        src32[i] = i - E;
        dst32[i] = i - E;
    }
}

__global__ void k_count(const int* __restrict__ dst32, int* __restrict__ deg,
                        int Etot) {
    int i = blockIdx.x * blockDim.x + threadIdx.x;
    if (i < Etot) atomicAdd(&deg[dst32[i]], 1);
}

// single-block exclusive scan (shfl-based), writes rowstart and cursor copy
__global__ __launch_bounds__(1024) void k_scan(const int* __restrict__ deg,
                                               int* __restrict__ rowstart,
                                               int* __restrict__ cursor, int N) {
    __shared__ int wsum[16];
    __shared__ int woff[16];
    __shared__ int chunk_total;
    __shared__ int base_s;
    int tid = threadIdx.x, lane = tid & 63, wid = tid >> 6;
    if (tid == 0) base_s = 0;
    __syncthreads();
    for (int start = 0; start < N; start += 1024) {
        int i = start + tid;
        int v = (i < N) ? deg[i] : 0;
        int x = v;
#pragma unroll
        for (int o = 1; o < 64; o <<= 1) {
            int t = __shfl_up(x, o, 64);
            if (lane >= o) x += t;
        }
        if (lane == 63) wsum[wid] = x;
        __syncthreads();
        if (wid == 0) {
            int y = (lane < 16) ? wsum[lane] : 0;
            int z = y;
#pragma unroll
            for (int o = 1; o < 16; o <<= 1) {
                int t = __shfl_up(z, o, 64);
                if (lane >= o) z += t;
            }
            if (lane < 16) woff[lane] = z - y;
            if (lane == 15) chunk_total = z;
        }
        __syncthreads();
        if (i < N) {
            int ex = base_s + woff[wid] + (x - v);
            rowstart[i] = ex;
            cursor[i] = ex;
        }
        __syncthreads();
        if (tid == 0) base_s += chunk_total;
        __syncthreads();
    }
    if (threadIdx.x == 0) rowstart[N] = base_s;
}

__global__ void k_fill(const int* __restrict__ src32, const int* __restrict__ dst32,
                       int* __restrict__ cursor, int* __restrict__ adj, int Etot) {
    int i = blockIdx.x * blockDim.x + threadIdx.x;
    if (i < Etot) {
        int d = dst32[i];
        int pos = atomicAdd(&cursor[d], 1);
        adj[pos] = src32[i];
    }
}

// --------------------------- f32 tiled GEMM ---------------------------------
// C[M,NC] = A[M,K] @ B[K,NC]; K %16==0, NC %64==0. 64x64 tile, 256 thr, 4x4.
__global__ __launch_bounds__(256) void k_gemm(const float* __restrict__ A,
                                              const float* __restrict__ B,
                                              float* __restrict__ C, int M,
                                              int K, int NC) {
    __shared__ float As[16][68];  // [kk][row]
    __shared__ float Bs[16][68];  // [kk][col]
    const int tid = threadIdx.x;
    const int tx = tid & 15, ty = tid >> 4;
    const int row0 = blockIdx.x * 64, col0 = blockIdx.y * 64;
    const int ar = tid >> 2, akq = (tid & 3) * 4;
    const int bk = tid >> 4, bc = (tid & 15) * 4;
    float acc[4][4] = {};
    for (int k0 = 0; k0 < K; k0 += 16) {
        float4 va = make_float4(0.f, 0.f, 0.f, 0.f);
        if (row0 + ar < M)
            va = *(const float4*)&A[(size_t)(row0 + ar) * K + k0 + akq];
        As[akq + 0][ar] = va.x;
        As[akq + 1][ar] = va.y;
        As[akq + 2][ar] = va.z;
        As[akq + 3][ar] = va.w;
        float4 vb = *(const float4*)&B[(size_t)(k0 + bk) * NC + col0 + bc];
        *(float4*)&Bs[bk][bc] = vb;
        __syncthreads();
#pragma unroll
        for (int kk = 0; kk < 16; kk++) {
            float4 a = *(const float4*)&As[kk][ty * 4];
            float4 b = *(const float4*)&Bs[kk][tx * 4];
            acc[0][0] += a.x * b.x; acc[0][1] += a.x * b.y;
            acc[0][2] += a.x * b.z; acc[0][3] += a.x * b.w;
            acc[1][0] += a.y * b.x; acc[1][1] += a.y * b.y;
            acc[1][2] += a.y * b.z; acc[1][3] += a.y * b.w;
            acc[2][0] += a.z * b.x; acc[2][1] += a.z * b.y;
            acc[2][2] += a.z * b.z; acc[2][3] += a.z * b.w;
            acc[3][0] += a.w * b.x; acc[3][1] += a.w * b.y;
            acc[3][2] += a.w * b.z; acc[3][3] += a.w * b.w;
        }
        __syncthreads();
    }
#pragma unroll
    for (int i = 0; i < 4; i++) {
        int r = row0 + ty * 4 + i;
        if (r < M)
            *(float4*)&C[(size_t)r * NC + col0 + tx * 4] =
                make_float4(acc[i][0], acc[i][1], acc[i][2], acc[i][3]);
    }
}

// --------------------------- attention scores -------------------------------
// conv1: one wave per node; lane l handles elems [8l,8l+8); heads = 16-lane
// groups. s_src[n,h] = <h1[n,h,:], a_src[h,:]>, same for a_dst.
__global__ void k_scores1(const float* __restrict__ h1,
                          const float* __restrict__ a_src,
                          const float* __restrict__ a_dst,
                          float* __restrict__ s_src, float* __restrict__ s_dst,
                          int N) {
    int gid = blockIdx.x * blockDim.x + threadIdx.x;
    int n = gid >> 6, lane = gid & 63;
    if (n >= N) return;
    const float4* hp = (const float4*)&h1[(size_t)n * D1 + lane * 8];
    float4 v0 = hp[0], v1 = hp[1];
    const float4* ap = (const float4*)&a_src[lane * 8];
    float4 a0 = ap[0], a1 = ap[1];
    const float4* bp = (const float4*)&a_dst[lane * 8];
    float4 b0 = bp[0], b1v = bp[1];
    float ss = v0.x * a0.x + v0.y * a0.y + v0.z * a0.z + v0.w * a0.w +
               v1.x * a1.x + v1.y * a1.y + v1.z * a1.z + v1.w * a1.w;
    float dd = v0.x * b0.x + v0.y * b0.y + v0.z * b0.z + v0.w * b0.w +
               v1.x * b1v.x + v1.y * b1v.y + v1.z * b1v.z + v1.w * b1v.w;
#pragma unroll
    for (int o = 1; o < 16; o <<= 1) {
        ss += __shfl_xor(ss, o, 64);
        dd += __shfl_xor(dd, o, 64);
    }
    if ((lane & 15) == 0) {
        int h = lane >> 4;
        s_src[(size_t)n * H1 + h] = ss;
        s_dst[(size_t)n * H1 + h] = dd;
    }
}

__global__ void k_scores2(const float* __restrict__ h2lin,
                          const float* __restrict__ a_src,
                          const float* __restrict__ a_dst,
                          float* __restrict__ s_src, float* __restrict__ s_dst,
                          int N) {
    int gid = blockIdx.x * blockDim.x + threadIdx.x;
    int n = gid >> 6, lane = gid & 63;
    if (n >= N) return;
    float v = h2lin[(size_t)n * C2 + lane];
    float ss = v * a_src[lane], dd = v * a_dst[lane];
#pragma unroll
    for (int o = 1; o < 64; o <<= 1) {
        ss += __shfl_xor(ss, o, 64);
        dd += __shfl_xor(dd, o, 64);
    }
    if (lane == 0) {
        s_src[n] = ss;
        s_dst[n] = dd;
    }
}

// --------------------------- conv1 aggregate --------------------------------
// one block (512 thr) per dst node: softmax over incoming edges, then
// out1[n, h*128+c] = elu( sum_j alpha[j,h]*h1[src_j, h*128+c] + b1 )
__global__ __launch_bounds__(512) void k_agg1(
    const float* __restrict__ h1, const float* __restrict__ s_src,
    const float* __restrict__ s_dst, const int* __restrict__ rowstart,
    const int* __restrict__ adj, const float* __restrict__ b1,
    float* __restrict__ out1, int N) {
    int n = blockIdx.x;
    int tid = threadIdx.x, lane = tid & 63, wid = tid >> 6;
    __shared__ float red[8][4];
    __shared__ float m_s[4], inv_s[4];
    __shared__ float salpha[64][4];
    __shared__ int ssrc[64];
    int beg = rowstart[n], end = rowstart[n + 1];
    float sd[4] = {s_dst[(size_t)n * 4 + 0], s_dst[(size_t)n * 4 + 1],
                   s_dst[(size_t)n * 4 + 2], s_dst[(size_t)n * 4 + 3]};
    // pass A1: max per head
    float m[4] = {-1e30f, -1e30f, -1e30f, -1e30f};
    for (int j = beg + tid; j < end; j += 512) {
        int s = adj[j];
#pragma unroll
        for (int h = 0; h < 4; h++) {
            float e = LRELU(s_src[(size_t)s * 4 + h] + sd[h]);
            m[h] = fmaxf(m[h], e);
        }
    }
#pragma unroll
    for (int h = 0; h < 4; h++)
#pragma unroll
        for (int o = 32; o >= 1; o >>= 1) m[h] = fmaxf(m[h], __shfl_xor(m[h], o, 64));
    if (lane == 0) {
        red[wid][0] = m[0]; red[wid][1] = m[1];
        red[wid][2] = m[2]; red[wid][3] = m[3];
    }
    __syncthreads();
    if (tid < 4) {
        float mm = -1e30f;
        for (int w = 0; w < 8; w++) mm = fmaxf(mm, red[w][tid]);
        m_s[tid] = mm;
    }
    __syncthreads();
    float mm[4] = {m_s[0], m_s[1], m_s[2], m_s[3]};
    // pass A2: denom per head
    float dn[4] = {0.f, 0.f, 0.f, 0.f};
    for (int j = beg + tid; j < end; j += 512) {
        int s = adj[j];
#pragma unroll
        for (int h = 0; h < 4; h++) {
            float e = LRELU(s_src[(size_t)s * 4 + h] + sd[h]);
            dn[h] += expf(e - mm[h]);
        }
    }
#pragma unroll
    for (int h = 0; h < 4; h++)
#pragma unroll
        for (int o = 32; o >= 1; o >>= 1) dn[h] += __shfl_xor(dn[h], o, 64);
    if (lane == 0) {
        red[wid][0] = dn[0]; red[wid][1] = dn[1];
        red[wid][2] = dn[2]; red[wid][3] = dn[3];
    }
    __syncthreads();
    if (tid < 4) {
        float s = 0.f;
        for (int w = 0; w < 8; w++) s += red[w][tid];
        inv_s[tid] = 1.f / (s + 1e-16f);
    }
    __syncthreads();
    // pass B: weighted gather. thread owns channel tid = h*128+c.
    int h = tid >> 7;
    float acc = 0.f;
    for (int c0 = beg; c0 < end; c0 += 64) {
        if (tid < 64) {
            int j = c0 + tid;
            if (j < end) {
                int s = adj[j];
                ssrc[tid] = s;
#pragma unroll
                for (int hh = 0; hh < 4; hh++) {
                    float e = LRELU(s_src[(size_t)s * 4 + hh] + sd[hh]);
                    salpha[tid][hh] = expf(e - m_s[hh]) * inv_s[hh];
                }
            }
        }
        __syncthreads();
        int cnt = min(64, end - c0);
        for (int j = 0; j < cnt; j++)
            acc += salpha[j][h] * h1[(size_t)ssrc[j] * D1 + tid];
        __syncthreads();
    }
    float r = acc + b1[tid];
    out1[(size_t)n * D1 + tid] = r > 0.f ? r : expm1f(r);
}

// --------------------------- conv2 aggregate --------------------------------
// one wave per dst node (H=1, C=64)
__global__ __launch_bounds__(64) void k_agg2(
    const float* __restrict__ h2lin, const float* __restrict__ s_src,
    const float* __restrict__ s_dst, const int* __restrict__ rowstart,
    const int* __restrict__ adj, const float* __restrict__ b2,
    float* __restrict__ h2, int N) {
    int n = blockIdx.x;
    int lane = threadIdx.x;
    __shared__ float salpha[64];
    __shared__ int ssrc[64];
    int beg = rowstart[n], end = rowstart[n + 1];
    float sd = s_dst[n];
    float m = -1e30f;
    for (int j = beg + lane; j < end; j += 64)
        m = fmaxf(m, LRELU(s_src[adj[j]] + sd));
#pragma unroll
    for (int o = 32; o >= 1; o >>= 1) m = fmaxf(m, __shfl_xor(m, o, 64));
    float dn = 0.f;
    for (int j = beg + lane; j < end; j += 64)
        dn += expf(LRELU(s_src[adj[j]] + sd) - m);
#pragma unroll
    for (int o = 32; o >= 1; o >>= 1) dn += __shfl_xor(dn, o, 64);
    float inv = 1.f / (dn + 1e-16f);
    float acc = 0.f;
    for (int c0 = beg; c0 < end; c0 += 64) {
        int j = c0 + lane;
        if (j < end) {
            int s = adj[j];
            ssrc[lane] = s;
            salpha[lane] = expf(LRELU(s_src[s] + sd) - m) * inv;
        }
        __syncthreads();
        int cnt = min(64, end - c0);
        for (int j2 = 0; j2 < cnt; j2++)
            acc += salpha[j2] * h2lin[(size_t)ssrc[j2] * C2 + lane];
        __syncthreads();
    }
    float r = acc + b2[lane];
    h2[(size_t)n * C2 + lane] = r > 0.f ? r : expm1f(r);
}

// --------------------------- MLP + LN + out ---------------------------------
__global__ __launch_bounds__(256) void k_mlp(
    const float* __restrict__ h2, const float* __restrict__ Wm1,
    const float* __restrict__ bm1, const float* __restrict__ g_ln,
    const float* __restrict__ b_ln, const float* __restrict__ Wm2,
    const float* __restrict__ bm2, float* __restrict__ out, int N) {
    __shared__ float w1[C2 * DM1];
    __shared__ float w2[DM1 * DM2];
    __shared__ float cb1[DM1], cg[DM1], cbl[DM1], cb2[DM2];
    int tid = threadIdx.x;
    for (int i = tid; i < C2 * DM1; i += 256) w1[i] = Wm1[i];
    for (int i = tid; i < DM1 * DM2; i += 256) w2[i] = Wm2[i];
    if (tid < DM1) {
        cb1[tid] = bm1[tid];
        cg[tid] = g_ln[tid];
        cbl[tid] = b_ln[tid];
    } else if (tid < DM1 + DM2) {
        cb2[tid - DM1] = bm2[tid - DM1];
    }
    __syncthreads();
    int n = blockIdx.x * 256 + tid;
    if (n >= N) return;
    float h[C2];
    const float4* hp = (const float4*)&h2[(size_t)n * C2];
#pragma unroll
    for (int i = 0; i < C2 / 4; i++) {
        float4 v = hp[i];
        h[4 * i] = v.x; h[4 * i + 1] = v.y;
        h[4 * i + 2] = v.z; h[4 * i + 3] = v.w;
    }
    float t[DM1];
#pragma unroll
    for (int j = 0; j < DM1; j++) {
        float a = cb1[j];
#pragma unroll
        for (int c = 0; c < C2; c++) a += h[c] * w1[c * DM1 + j];
        t[j] = a;
    }
    float mu = 0.f;
#pragma unroll
    for (int j = 0; j < DM1; j++) mu += t[j];
    mu *= (1.f / DM1);
    float var = 0.f;
#pragma unroll
    for (int j = 0; j < DM1; j++) {
        float d = t[j] - mu;
        var += d * d;
    }
    var *= (1.f / DM1);
    float rs = rsqrtf(var + 1e-5f);
#pragma unroll
    for (int j = 0; j < DM1; j++) {
        float z = (t[j] - mu) * rs * cg[j] + cbl[j];
        t[j] = z > 0.f ? z : 0.f;
    }
    float o[DM2];
#pragma unroll
    for (int k = 0; k < DM2; k++) {
        float a = cb2[k];
#pragma unroll
        for (int j = 0; j < DM1; j++) a += t[j] * w2[j * DM2 + k];
        o[k] = a;
    }
    float4* op = (float4*)&out[(size_t)n * DM2];
    op[0] = make_float4(o[0], o[1], o[2], o[3]);
    op[1] = make_float4(o[4], o[5], o[6], o[7]);
    op[2] = make_float4(o[8], o[9], o[10], o[11]);
    op[3] = make_float4(o[12], o[13], o[14], o[15]);
}

// ---------------------------------------------------------------------------
extern "C" void kernel_launch(void* const* d_in, const int* in_sizes, int n_in,
                              void* d_out, int out_size, void* d_ws,
                              size_t ws_size, hipStream_t stream) {
    const float* x      = (const float*)d_in[0];
    const void*  ei     = d_in[1];
    const float* W1     = (const float*)d_in[3];
    const float* a_src1 = (const float*)d_in[4];
    const float* a_dst1 = (const float*)d_in[5];
    const float* b1     = (const float*)d_in[6];
    const float* W2     = (const float*)d_in[7];
    const float* a_src2 = (const float*)d_in[8];
    const float* a_dst2 = (const float*)d_in[9];
    const float* b2     = (const float*)d_in[10];
    const float* Wm1    = (const float*)d_in[11];
    const float* bm1    = (const float*)d_in[12];
    const float* g_ln   = (const float*)d_in[13];
    const float* b_ln   = (const float*)d_in[14];
    const float* Wm2    = (const float*)d_in[15];
    const float* bm2    = (const float*)d_in[16];

    const int N    = in_sizes[0] / F_IN;
    const int E    = in_sizes[1] / 2;
    const int Etot = E + N;

    char* ws = (char*)d_ws;
    size_t off = 0;
    auto alloc = [&](size_t bytes) {
        size_t o = off;
        off += (bytes + 255) & ~(size_t)255;
        return o;
    };
    int*   flag     = (int*)(ws + alloc(4));
    int*   src32    = (int*)(ws + alloc((size_t)Etot * 4));
    int*   dst32    = (int*)(ws + alloc((size_t)Etot * 4));
    int*   deg      = (int*)(ws + alloc((size_t)N * 4));
    int*   rowstart = (int*)(ws + alloc((size_t)(N + 1) * 4));
    int*   cursor   = (int*)(ws + alloc((size_t)N * 4));
    int*   adj      = (int*)(ws + alloc((size_t)Etot * 4));
    float* s_src1   = (float*)(ws + alloc((size_t)N * H1 * 4));
    float* s_dst1   = (float*)(ws + alloc((size_t)N * H1 * 4));
    float* h1       = (float*)(ws + alloc((size_t)N * D1 * 4));
    float* out1     = (float*)(ws + alloc((size_t)N * D1 * 4));
    // reuse: h1 region is free after conv2-GEMM reads -> h2lin and h2 live there
    float* h2lin = h1;
    float* h2    = (float*)((char*)h1 + (size_t)N * C2 * 4);
    float* s_src2 = s_src1;
    float* s_dst2 = s_dst1;

    hipMemsetAsync(deg, 0, (size_t)N * 4, stream);
    k_detect<<<1, 256, 0, stream>>>(ei, E, flag);
    k_convert<<<(Etot + 255) / 256, 256, 0, stream>>>(ei, flag, E, N, src32, dst32);
    k_count<<<(Etot + 255) / 256, 256, 0, stream>>>(dst32, deg, Etot);
    k_scan<<<1, 1024, 0, stream>>>(deg, rowstart, cursor, N);
    k_fill<<<(Etot + 255) / 256, 256, 0, stream>>>(src32, dst32, cursor, adj, Etot);

    // conv1
    k_gemm<<<dim3((N + 63) / 64, D1 / 64), 256, 0, stream>>>(x, W1, h1, N, F_IN, D1);
    k_scores1<<<((size_t)N * 64 + 255) / 256, 256, 0, stream>>>(h1, a_src1, a_dst1,
                                                                s_src1, s_dst1, N);
    k_agg1<<<N, 512, 0, stream>>>(h1, s_src1, s_dst1, rowstart, adj, b1, out1, N);

    // conv2
    k_gemm<<<dim3((N + 63) / 64, C2 / 64), 256, 0, stream>>>(out1, W2, h2lin, N, D1, C2);
    k_scores2<<<((size_t)N * 64 + 255) / 256, 256, 0, stream>>>(h2lin, a_src2, a_dst2,
                                                                s_src2, s_dst2, N);
    k_agg2<<<N, 64, 0, stream>>>(h2lin, s_src2, s_dst2, rowstart, adj, b2, h2, N);

    // MLP head
    k_mlp<<<(N + 255) / 256, 256, 0, stream>>>(h2, Wm1, bm1, g_ln, b_ln, Wm2, bm2,
                                               (float*)d_out, N);
}

// Round 3
// 489.093 us; speedup vs baseline: 1.5300x; 1.5300x over previous
//
#include <hip/hip_runtime.h>
#include <cmath>

// ---------------------------------------------------------------------------
// SpectralGAT: 2-layer GAT (H1=4,C1=128 concat -> 512; H=1,C2=64) + MLP.
// bf16 MFMA for both GEMMs; h1/out1 stored bf16 (L3-resident gather);
// softmax/aggregation accumulate f32. CSR built on device every call.
// ---------------------------------------------------------------------------

#define F_IN 128
#define H1   4
#define C1   128
#define D1   512   // H1*C1
#define C2   64
#define DM1  32
#define DM2  16

#define LRELU(x) ((x) > 0.f ? (x) : 0.2f * (x))

typedef float f32x4 __attribute__((ext_vector_type(4)));
typedef short short8 __attribute__((ext_vector_type(8)));

static __device__ __forceinline__ float bf2f(unsigned short u) {
    return __builtin_bit_cast(float, (unsigned)u << 16);
}
static __device__ __forceinline__ unsigned short f2bf(float f) {
    unsigned u = __builtin_bit_cast(unsigned, f);
    u = (u + 0x7fffu + ((u >> 16) & 1u)) >> 16;
    return (unsigned short)u;
}

// --------------------------- edge dtype detect ------------------------------
__global__ void k_detect(const void* ei, int E, int* flag) {
    __shared__ int any;
    if (threadIdx.x == 0) any = 0;
    __syncthreads();
    const int* p = (const int*)ei;
    int cnt = E < 4096 ? E : 4096;
    int stride = E / cnt;
    int local = 0;
    for (int i = threadIdx.x; i < cnt; i += blockDim.x) {
        long long idx = (long long)i * stride;
        local |= p[2 * idx + 1];
    }
    if (local) atomicOr(&any, 1);
    __syncthreads();
    if (threadIdx.x == 0) *flag = (any == 0) ? 1 : 0;
}

__global__ void k_convert(const void* ei, const int* flag, int E, int N,
                          int* src32, int* dst32) {
    int i = blockIdx.x * blockDim.x + threadIdx.x;
    int Etot = E + N;
    if (i >= Etot) return;
    if (i < E) {
        int s, d;
        if (*flag) {
            const long long* q = (const long long*)ei;
            s = (int)q[i];
            d = (int)q[(size_t)E + i];
        } else {
            const int* q = (const int*)ei;
            s = q[i];
            d = q[(size_t)E + i];
        }
        src32[i] = s;
        dst32[i] = d;
    } else {
        src32[i] = i - E;
        dst32[i] = i - E;
    }
}

__global__ void k_count(const int* __restrict__ dst32, int* __restrict__ deg,
                        int Etot) {
    int i = blockIdx.x * blockDim.x + threadIdx.x;
    if (i < Etot) atomicAdd(&deg[dst32[i]], 1);
}

__global__ __launch_bounds__(1024) void k_scan(const int* __restrict__ deg,
                                               int* __restrict__ rowstart,
                                               int* __restrict__ cursor, int N) {
    __shared__ int wsum[16];
    __shared__ int woff[16];
    __shared__ int chunk_total;
    __shared__ int base_s;
    int tid = threadIdx.x, lane = tid & 63, wid = tid >> 6;
    if (tid == 0) base_s = 0;
    __syncthreads();
    for (int start = 0; start < N; start += 1024) {
        int i = start + tid;
        int v = (i < N) ? deg[i] : 0;
        int x = v;
#pragma unroll
        for (int o = 1; o < 64; o <<= 1) {
            int t = __shfl_up(x, o, 64);
            if (lane >= o) x += t;
        }
        if (lane == 63) wsum[wid] = x;
        __syncthreads();
        if (wid == 0) {
            int y = (lane < 16) ? wsum[lane] : 0;
            int z = y;
#pragma unroll
            for (int o = 1; o < 16; o <<= 1) {
                int t = __shfl_up(z, o, 64);
                if (lane >= o) z += t;
            }
            if (lane < 16) woff[lane] = z - y;
            if (lane == 15) chunk_total = z;
        }
        __syncthreads();
        if (i < N) {
            int ex = base_s + woff[wid] + (x - v);
            rowstart[i] = ex;
            cursor[i] = ex;
        }
        __syncthreads();
        if (tid == 0) base_s += chunk_total;
        __syncthreads();
    }
    if (threadIdx.x == 0) rowstart[N] = base_s;
}

__global__ void k_fill(const int* __restrict__ src32, const int* __restrict__ dst32,
                       int* __restrict__ cursor, int* __restrict__ adj, int Etot) {
    int i = blockIdx.x * blockDim.x + threadIdx.x;
    if (i < Etot) {
        int d = dst32[i];
        int pos = atomicAdd(&cursor[d], 1);
        adj[pos] = src32[i];
    }
}

// --------------------------- f32 -> bf16 conversions ------------------------
// 8 elems per thread
__global__ void k_cvt_bf16(const float* __restrict__ in,
                           unsigned short* __restrict__ out, int n8) {
    int i = blockIdx.x * blockDim.x + threadIdx.x;
    if (i >= n8) return;
    const float4* p = (const float4*)(in + (size_t)i * 8);
    float4 a = p[0], b = p[1];
    unsigned short r[8] = {f2bf(a.x), f2bf(a.y), f2bf(a.z), f2bf(a.w),
                           f2bf(b.x), f2bf(b.y), f2bf(b.z), f2bf(b.w)};
    *(short8*)(out + (size_t)i * 8) = *(const short8*)r;
}

// Wt[n*K + k] = bf16(W[k*NC + n])
__global__ void k_transpose_bf16(const float* __restrict__ W,
                                 unsigned short* __restrict__ Wt, int K, int NC) {
    int i = blockIdx.x * blockDim.x + threadIdx.x;
    if (i >= K * NC) return;
    int nn = i / K, kk = i - nn * K;
    Wt[i] = f2bf(W[(size_t)kk * NC + nn]);
}

// --------------------------- bf16 MFMA GEMM ---------------------------------
// C[M,NC] = A[M,K] @ Bt[NC,K]^T.  K % 64 == 0.  256 threads = 4 waves.
// BM = WM*MF*16, BN = WN*NF*16. Fragment layout: A/B lane = (k-group l>>4,
// row/col l&15), 8 contiguous k per lane; C/D col=l&15, row=(l>>4)*4+r.
template <int WM, int WN, int MF, int NF, bool OUT_BF16>
__global__ __launch_bounds__(256) void k_gemm_bf16(
    const unsigned short* __restrict__ A, const unsigned short* __restrict__ Bt,
    void* __restrict__ C, int M, int K, int NC) {
    constexpr int BM = WM * MF * 16;
    constexpr int BN = WN * NF * 16;
    constexpr int BK = 64;
    constexpr int LDK = BK + 8;  // padded stride: 144 B, 16B-aligned rows
    __shared__ unsigned short As[BM][LDK];
    __shared__ unsigned short Bs[BN][LDK];
    const int tid = threadIdx.x;
    const int row0 = blockIdx.x * BM, col0 = blockIdx.y * BN;
    const int wave = tid >> 6, lane = tid & 63;
    const int wr = wave / WN, wc = wave % WN;
    const int lrow = lane & 15, lkg = lane >> 4;
    f32x4 acc[MF][NF] = {};
    for (int k0 = 0; k0 < K; k0 += BK) {
        for (int i = tid; i < BM * BK / 8; i += 256) {
            int r = i >> 3, kq = (i & 7) * 8;
            short8 v = {};
            if (row0 + r < M)
                v = *(const short8*)&A[(size_t)(row0 + r) * K + k0 + kq];
            *(short8*)&As[r][kq] = v;
        }
        for (int i = tid; i < BN * BK / 8; i += 256) {
            int r = i >> 3, kq = (i & 7) * 8;
            short8 v = *(const short8*)&Bt[(size_t)(col0 + r) * K + k0 + kq];
            *(short8*)&Bs[r][kq] = v;
        }
        __syncthreads();
#pragma unroll
        for (int kk = 0; kk < BK; kk += 32) {
            short8 af[MF], bf[NF];
#pragma unroll
            for (int m = 0; m < MF; m++)
                af[m] = *(const short8*)&As[wr * MF * 16 + m * 16 + lrow][kk + lkg * 8];
#pragma unroll
            for (int n = 0; n < NF; n++)
                bf[n] = *(const short8*)&Bs[wc * NF * 16 + n * 16 + lrow][kk + lkg * 8];
#pragma unroll
            for (int m = 0; m < MF; m++)
#pragma unroll
                for (int n = 0; n < NF; n++)
                    acc[m][n] = __builtin_amdgcn_mfma_f32_16x16x32_bf16(
                        af[m], bf[n], acc[m][n], 0, 0, 0);
        }
        __syncthreads();
    }
#pragma unroll
    for (int m = 0; m < MF; m++)
#pragma unroll
        for (int n = 0; n < NF; n++)
#pragma unroll
            for (int r = 0; r < 4; r++) {
                int gr = row0 + wr * MF * 16 + m * 16 + lkg * 4 + r;
                int gc = col0 + wc * NF * 16 + n * 16 + lrow;
                if (gr < M) {
                    if (OUT_BF16)
                        ((unsigned short*)C)[(size_t)gr * NC + gc] = f2bf(acc[m][n][r]);
                    else
                        ((float*)C)[(size_t)gr * NC + gc] = acc[m][n][r];
                }
            }
}

// --------------------------- attention scores -------------------------------
// conv1 from bf16 h1: one wave/node, lane l -> elems [8l,8l+8), head = l>>4.
__global__ void k_scores1(const unsigned short* __restrict__ h1b,
                          const float* __restrict__ a_src,
                          const float* __restrict__ a_dst,
                          float* __restrict__ s_src, float* __restrict__ s_dst,
                          int N) {
    int gid = blockIdx.x * blockDim.x + threadIdx.x;
    int n = gid >> 6, lane = gid & 63;
    if (n >= N) return;
    short8 hv = *(const short8*)&h1b[(size_t)n * D1 + lane * 8];
    float h[8];
#pragma unroll
    for (int j = 0; j < 8; j++) h[j] = bf2f((unsigned short)hv[j]);
    const float4* ap = (const float4*)&a_src[lane * 8];
    float4 a0 = ap[0], a1 = ap[1];
    const float4* bp = (const float4*)&a_dst[lane * 8];
    float4 b0 = bp[0], b1v = bp[1];
    float ss = h[0] * a0.x + h[1] * a0.y + h[2] * a0.z + h[3] * a0.w +
               h[4] * a1.x + h[5] * a1.y + h[6] * a1.z + h[7] * a1.w;
    float dd = h[0] * b0.x + h[1] * b0.y + h[2] * b0.z + h[3] * b0.w +
               h[4] * b1v.x + h[5] * b1v.y + h[6] * b1v.z + h[7] * b1v.w;
#pragma unroll
    for (int o = 1; o < 16; o <<= 1) {
        ss += __shfl_xor(ss, o, 64);
        dd += __shfl_xor(dd, o, 64);
    }
    if ((lane & 15) == 0) {
        int h4 = lane >> 4;
        s_src[(size_t)n * H1 + h4] = ss;
        s_dst[(size_t)n * H1 + h4] = dd;
    }
}

__global__ void k_scores2(const float* __restrict__ h2lin,
                          const float* __restrict__ a_src,
                          const float* __restrict__ a_dst,
                          float* __restrict__ s_src, float* __restrict__ s_dst,
                          int N) {
    int gid = blockIdx.x * blockDim.x + threadIdx.x;
    int n = gid >> 6, lane = gid & 63;
    if (n >= N) return;
    float v = h2lin[(size_t)n * C2 + lane];
    float ss = v * a_src[lane], dd = v * a_dst[lane];
#pragma unroll
    for (int o = 1; o < 64; o <<= 1) {
        ss += __shfl_xor(ss, o, 64);
        dd += __shfl_xor(dd, o, 64);
    }
    if (lane == 0) {
        s_src[n] = ss;
        s_dst[n] = dd;
    }
}

// --------------------------- conv1 aggregate --------------------------------
// 256 threads/dst node; thread owns channels (2t,2t+1); head = t>>6.
__global__ __launch_bounds__(256) void k_agg1(
    const unsigned short* __restrict__ h1b, const float* __restrict__ s_src,
    const float* __restrict__ s_dst, const int* __restrict__ rowstart,
    const int* __restrict__ adj, const float* __restrict__ b1,
    unsigned short* __restrict__ out1, int N) {
    int n = blockIdx.x;
    int tid = threadIdx.x, lane = tid & 63, wid = tid >> 6;
    __shared__ float red[4][4];
    __shared__ float m_s[4], inv_s[4];
    __shared__ float salpha[64][4];
    __shared__ int ssrc[64];
    int beg = rowstart[n], end = rowstart[n + 1];
    float sd[4] = {s_dst[(size_t)n * 4 + 0], s_dst[(size_t)n * 4 + 1],
                   s_dst[(size_t)n * 4 + 2], s_dst[(size_t)n * 4 + 3]};
    // pass A1: max per head
    float m[4] = {-1e30f, -1e30f, -1e30f, -1e30f};
    for (int j = beg + tid; j < end; j += 256) {
        int s = adj[j];
#pragma unroll
        for (int h = 0; h < 4; h++) {
            float e = LRELU(s_src[(size_t)s * 4 + h] + sd[h]);
            m[h] = fmaxf(m[h], e);
        }
    }
#pragma unroll
    for (int h = 0; h < 4; h++)
#pragma unroll
        for (int o = 32; o >= 1; o >>= 1) m[h] = fmaxf(m[h], __shfl_xor(m[h], o, 64));
    if (lane == 0) {
        red[wid][0] = m[0]; red[wid][1] = m[1];
        red[wid][2] = m[2]; red[wid][3] = m[3];
    }
    __syncthreads();
    if (tid < 4) {
        float mm = -1e30f;
        for (int w = 0; w < 4; w++) mm = fmaxf(mm, red[w][tid]);
        m_s[tid] = mm;
    }
    __syncthreads();
    float mm[4] = {m_s[0], m_s[1], m_s[2], m_s[3]};
    // pass A2: denom per head
    float dn[4] = {0.f, 0.f, 0.f, 0.f};
    for (int j = beg + tid; j < end; j += 256) {
        int s = adj[j];
#pragma unroll
        for (int h = 0; h < 4; h++) {
            float e = LRELU(s_src[(size_t)s * 4 + h] + sd[h]);
            dn[h] += expf(e - mm[h]);
        }
    }
#pragma unroll
    for (int h = 0; h < 4; h++)
#pragma unroll
        for (int o = 32; o >= 1; o >>= 1) dn[h] += __shfl_xor(dn[h], o, 64);
    if (lane == 0) {
        red[wid][0] = dn[0]; red[wid][1] = dn[1];
        red[wid][2] = dn[2]; red[wid][3] = dn[3];
    }
    __syncthreads();
    if (tid < 4) {
        float s = 0.f;
        for (int w = 0; w < 4; w++) s += red[w][tid];
        inv_s[tid] = 1.f / (s + 1e-16f);
    }
    __syncthreads();
    // pass B: weighted gather (bf16 rows, f32 accum)
    int h = tid >> 6;
    float acc0 = 0.f, acc1 = 0.f;
    for (int c0 = beg; c0 < end; c0 += 64) {
        if (tid < 64) {
            int j = c0 + tid;
            if (j < end) {
                int s = adj[j];
                ssrc[tid] = s;
#pragma unroll
                for (int hh = 0; hh < 4; hh++) {
                    float e = LRELU(s_src[(size_t)s * 4 + hh] + sd[hh]);
                    salpha[tid][hh] = expf(e - m_s[hh]) * inv_s[hh];
                }
            }
        }
        __syncthreads();
        int cnt = min(64, end - c0);
        for (int j = 0; j < cnt; j++) {
            unsigned v = *(const unsigned*)&h1b[(size_t)ssrc[j] * D1 + 2 * tid];
            float a = salpha[j][h];
            acc0 += a * bf2f((unsigned short)(v & 0xffffu));
            acc1 += a * bf2f((unsigned short)(v >> 16));
        }
        __syncthreads();
    }
    float r0 = acc0 + b1[2 * tid];
    float r1 = acc1 + b1[2 * tid + 1];
    r0 = r0 > 0.f ? r0 : expm1f(r0);
    r1 = r1 > 0.f ? r1 : expm1f(r1);
    unsigned outw = (unsigned)f2bf(r0) | ((unsigned)f2bf(r1) << 16);
    *(unsigned*)&out1[(size_t)n * D1 + 2 * tid] = outw;
}

// --------------------------- conv2 aggregate --------------------------------
__global__ __launch_bounds__(64) void k_agg2(
    const float* __restrict__ h2lin, const float* __restrict__ s_src,
    const float* __restrict__ s_dst, const int* __restrict__ rowstart,
    const int* __restrict__ adj, const float* __restrict__ b2,
    float* __restrict__ h2, int N) {
    int n = blockIdx.x;
    int lane = threadIdx.x;
    __shared__ float salpha[64];
    __shared__ int ssrc[64];
    int beg = rowstart[n], end = rowstart[n + 1];
    float sd = s_dst[n];
    float m = -1e30f;
    for (int j = beg + lane; j < end; j += 64)
        m = fmaxf(m, LRELU(s_src[adj[j]] + sd));
#pragma unroll
    for (int o = 32; o >= 1; o >>= 1) m = fmaxf(m, __shfl_xor(m, o, 64));
    float dn = 0.f;
    for (int j = beg + lane; j < end; j += 64)
        dn += expf(LRELU(s_src[adj[j]] + sd) - m);
#pragma unroll
    for (int o = 32; o >= 1; o >>= 1) dn += __shfl_xor(dn, o, 64);
    float inv = 1.f / (dn + 1e-16f);
    float acc = 0.f;
    for (int c0 = beg; c0 < end; c0 += 64) {
        int j = c0 + lane;
        if (j < end) {
            int s = adj[j];
            ssrc[lane] = s;
            salpha[lane] = expf(LRELU(s_src[s] + sd) - m) * inv;
        }
        __syncthreads();
        int cnt = min(64, end - c0);
        for (int j2 = 0; j2 < cnt; j2++)
            acc += salpha[j2] * h2lin[(size_t)ssrc[j2] * C2 + lane];
        __syncthreads();
    }
    float r = acc + b2[lane];
    h2[(size_t)n * C2 + lane] = r > 0.f ? r : expm1f(r);
}

// --------------------------- MLP + LN + out ---------------------------------
__global__ __launch_bounds__(256) void k_mlp(
    const float* __restrict__ h2, const float* __restrict__ Wm1,
    const float* __restrict__ bm1, const float* __restrict__ g_ln,
    const float* __restrict__ b_ln, const float* __restrict__ Wm2,
    const float* __restrict__ bm2, float* __restrict__ out, int N) {
    __shared__ float w1[C2 * DM1];
    __shared__ float w2[DM1 * DM2];
    __shared__ float cb1[DM1], cg[DM1], cbl[DM1], cb2[DM2];
    int tid = threadIdx.x;
    for (int i = tid; i < C2 * DM1; i += 256) w1[i] = Wm1[i];
    for (int i = tid; i < DM1 * DM2; i += 256) w2[i] = Wm2[i];
    if (tid < DM1) {
        cb1[tid] = bm1[tid];
        cg[tid] = g_ln[tid];
        cbl[tid] = b_ln[tid];
    } else if (tid < DM1 + DM2) {
        cb2[tid - DM1] = bm2[tid - DM1];
    }
    __syncthreads();
    int n = blockIdx.x * 256 + tid;
    if (n >= N) return;
    float h[C2];
    const float4* hp = (const float4*)&h2[(size_t)n * C2];
#pragma unroll
    for (int i = 0; i < C2 / 4; i++) {
        float4 v = hp[i];
        h[4 * i] = v.x; h[4 * i + 1] = v.y;
        h[4 * i + 2] = v.z; h[4 * i + 3] = v.w;
    }
    float t[DM1];
#pragma unroll
    for (int j = 0; j < DM1; j++) {
        float a = cb1[j];
#pragma unroll
        for (int c = 0; c < C2; c++) a += h[c] * w1[c * DM1 + j];
        t[j] = a;
    }
    float mu = 0.f;
#pragma unroll
    for (int j = 0; j < DM1; j++) mu += t[j];
    mu *= (1.f / DM1);
    float var = 0.f;
#pragma unroll
    for (int j = 0; j < DM1; j++) {
        float d = t[j] - mu;
        var += d * d;
    }
    var *= (1.f / DM1);
    float rs = rsqrtf(var + 1e-5f);
#pragma unroll
    for (int j = 0; j < DM1; j++) {
        float z = (t[j] - mu) * rs * cg[j] + cbl[j];
        t[j] = z > 0.f ? z : 0.f;
    }
    float o[DM2];
#pragma unroll
    for (int k = 0; k < DM2; k++) {
        float a = cb2[k];
#pragma unroll
        for (int j = 0; j < DM1; j++) a += t[j] * w2[j * DM2 + k];
        o[k] = a;
    }
    float4* op = (float4*)&out[(size_t)n * DM2];
    op[0] = make_float4(o[0], o[1], o[2], o[3]);
    op[1] = make_float4(o[4], o[5], o[6], o[7]);
    op[2] = make_float4(o[8], o[9], o[10], o[11]);
    op[3] = make_float4(o[12], o[13], o[14], o[15]);
}

// ---------------------------------------------------------------------------
extern "C" void kernel_launch(void* const* d_in, const int* in_sizes, int n_in,
                              void* d_out, int out_size, void* d_ws,
                              size_t ws_size, hipStream_t stream) {
    const float* x      = (const float*)d_in[0];
    const void*  ei     = d_in[1];
    const float* W1     = (const float*)d_in[3];
    const float* a_src1 = (const float*)d_in[4];
    const float* a_dst1 = (const float*)d_in[5];
    const float* b1     = (const float*)d_in[6];
    const float* W2     = (const float*)d_in[7];
    const float* a_src2 = (const float*)d_in[8];
    const float* a_dst2 = (const float*)d_in[9];
    const float* b2     = (const float*)d_in[10];
    const float* Wm1    = (const float*)d_in[11];
    const float* bm1    = (const float*)d_in[12];
    const float* g_ln   = (const float*)d_in[13];
    const float* b_ln   = (const float*)d_in[14];
    const float* Wm2    = (const float*)d_in[15];
    const float* bm2    = (const float*)d_in[16];

    const int N    = in_sizes[0] / F_IN;
    const int E    = in_sizes[1] / 2;
    const int Etot = E + N;

    char* ws = (char*)d_ws;
    size_t off = 0;
    auto alloc = [&](size_t bytes) {
        size_t o = off;
        off += (bytes + 255) & ~(size_t)255;
        return o;
    };
    int*   flag     = (int*)(ws + alloc(4));
    int*   src32    = (int*)(ws + alloc((size_t)Etot * 4));
    int*   dst32    = (int*)(ws + alloc((size_t)Etot * 4));
    int*   deg      = (int*)(ws + alloc((size_t)N * 4));
    int*   rowstart = (int*)(ws + alloc((size_t)(N + 1) * 4));
    int*   cursor   = (int*)(ws + alloc((size_t)N * 4));
    int*   adj      = (int*)(ws + alloc((size_t)Etot * 4));
    float* s_src1   = (float*)(ws + alloc((size_t)N * H1 * 4));
    float* s_dst1   = (float*)(ws + alloc((size_t)N * H1 * 4));
    unsigned short* xb   = (unsigned short*)(ws + alloc((size_t)N * F_IN * 2));
    unsigned short* W1t  = (unsigned short*)(ws + alloc((size_t)F_IN * D1 * 2));
    unsigned short* W2t  = (unsigned short*)(ws + alloc((size_t)D1 * C2 * 2));
    unsigned short* h1b  = (unsigned short*)(ws + alloc((size_t)N * D1 * 2));
    unsigned short* out1 = (unsigned short*)(ws + alloc((size_t)N * D1 * 2));
    float* h2lin = (float*)(ws + alloc((size_t)N * C2 * 4));
    float* h2    = (float*)(ws + alloc((size_t)N * C2 * 4));
    float* s_src2 = s_src1;
    float* s_dst2 = s_dst1;

    hipMemsetAsync(deg, 0, (size_t)N * 4, stream);
    k_detect<<<1, 256, 0, stream>>>(ei, E, flag);
    k_convert<<<(Etot + 255) / 256, 256, 0, stream>>>(ei, flag, E, N, src32, dst32);
    k_count<<<(Etot + 255) / 256, 256, 0, stream>>>(dst32, deg, Etot);
    k_scan<<<1, 1024, 0, stream>>>(deg, rowstart, cursor, N);
    k_fill<<<(Etot + 255) / 256, 256, 0, stream>>>(src32, dst32, cursor, adj, Etot);

    // bf16 conversions
    k_cvt_bf16<<<(N * F_IN / 8 + 255) / 256, 256, 0, stream>>>(x, xb, N * F_IN / 8);
    k_transpose_bf16<<<(F_IN * D1 + 255) / 256, 256, 0, stream>>>(W1, W1t, F_IN, D1);
    k_transpose_bf16<<<(D1 * C2 + 255) / 256, 256, 0, stream>>>(W2, W2t, D1, C2);

    // conv1: h1 = x@W1 (bf16 MFMA, 128x128 tile), scores, aggregate
    k_gemm_bf16<2, 2, 4, 4, true>
        <<<dim3((N + 127) / 128, D1 / 128), 256, 0, stream>>>(xb, W1t, h1b, N, F_IN, D1);
    k_scores1<<<((size_t)N * 64 + 255) / 256, 256, 0, stream>>>(h1b, a_src1, a_dst1,
                                                                s_src1, s_dst1, N);
    k_agg1<<<N, 256, 0, stream>>>(h1b, s_src1, s_dst1, rowstart, adj, b1, out1, N);

    // conv2: h2lin = out1@W2 (bf16 MFMA, 128x64 tile, f32 out)
    k_gemm_bf16<4, 1, 2, 4, false>
        <<<dim3((N + 127) / 128, 1), 256, 0, stream>>>(out1, W2t, h2lin, N, D1, C2);
    k_scores2<<<((size_t)N * 64 + 255) / 256, 256, 0, stream>>>(h2lin, a_src2, a_dst2,
                                                                s_src2, s_dst2, N);
    k_agg2<<<N, 64, 0, stream>>>(h2lin, s_src2, s_dst2, rowstart, adj, b2, h2, N);

    // MLP head
    k_mlp<<<(N + 255) / 256, 256, 0, stream>>>(h2, Wm1, bm1, g_ln, b_ln, Wm2, bm2,
                                               (float*)d_out, N);
}

// Round 4
// 374.756 us; speedup vs baseline: 1.9968x; 1.3051x over previous
//
#include <hip/hip_runtime.h>
#include <cmath>

// ---------------------------------------------------------------------------
// SpectralGAT: 2-layer GAT (H1=4,C1=128 concat -> 512; H=1,C2=64) + MLP.
// bf16 MFMA GEMMs; h1/out1 bf16; wave-per-node aggregation (no LDS/barriers);
// parallel 3-phase CSR scan. CSR rebuilt on device every call.
// ---------------------------------------------------------------------------

#define F_IN 128
#define H1   4
#define C1   128
#define D1   512   // H1*C1
#define C2   64
#define DM1  32
#define DM2  16

#define LRELU(x) ((x) > 0.f ? (x) : 0.2f * (x))

typedef float f32x4 __attribute__((ext_vector_type(4)));
typedef short short8 __attribute__((ext_vector_type(8)));

static __device__ __forceinline__ float bf2f(unsigned short u) {
    return __builtin_bit_cast(float, (unsigned)u << 16);
}
static __device__ __forceinline__ unsigned short f2bf(float f) {
    unsigned u = __builtin_bit_cast(unsigned, f);
    u = (u + 0x7fffu + ((u >> 16) & 1u)) >> 16;
    return (unsigned short)u;
}

// --------------------------- edge dtype detect ------------------------------
__global__ void k_detect(const void* ei, int E, int* flag) {
    __shared__ int any;
    if (threadIdx.x == 0) any = 0;
    __syncthreads();
    const int* p = (const int*)ei;
    int cnt = E < 4096 ? E : 4096;
    int stride = E / cnt;
    int local = 0;
    for (int i = threadIdx.x; i < cnt; i += blockDim.x) {
        long long idx = (long long)i * stride;
        local |= p[2 * idx + 1];
    }
    if (local) atomicOr(&any, 1);
    __syncthreads();
    if (threadIdx.x == 0) *flag = (any == 0) ? 1 : 0;
}

// convert edge_index -> int32 src/dst (+self-loops) and count degrees
__global__ void k_convert(const void* ei, const int* flag, int E, int N,
                          int* src32, int* dst32, int* deg) {
    int i = blockIdx.x * blockDim.x + threadIdx.x;
    int Etot = E + N;
    if (i >= Etot) return;
    int s, d;
    if (i < E) {
        if (*flag) {
            const long long* q = (const long long*)ei;
            s = (int)q[i];
            d = (int)q[(size_t)E + i];
        } else {
            const int* q = (const int*)ei;
            s = q[i];
            d = q[(size_t)E + i];
        }
    } else {
        s = i - E;
        d = i - E;
    }
    src32[i] = s;
    dst32[i] = d;
    atomicAdd(&deg[d], 1);
}

// --------------------------- parallel scan (3 phases) -----------------------
// phase 1: per-block (1024 elems) sums
__global__ __launch_bounds__(256) void k_scan1(const int* __restrict__ deg,
                                               int* __restrict__ bsum, int N) {
    int t = threadIdx.x;
    int base = blockIdx.x * 1024 + t * 4;
    int s = 0;
    if (base + 3 < N) {
        int4 v = *(const int4*)&deg[base];
        s = v.x + v.y + v.z + v.w;
    } else {
        for (int k = 0; k < 4; k++)
            if (base + k < N) s += deg[base + k];
    }
#pragma unroll
    for (int o = 1; o < 64; o <<= 1) s += __shfl_xor(s, o, 64);
    __shared__ int ws[4];
    if ((t & 63) == 0) ws[t >> 6] = s;
    __syncthreads();
    if (t == 0) bsum[blockIdx.x] = ws[0] + ws[1] + ws[2] + ws[3];
}

// phase 2: exclusive scan of block sums (nb <= 1024), single block
__global__ __launch_bounds__(1024) void k_scan2(const int* __restrict__ bsum,
                                                int* __restrict__ boff, int nb) {
    __shared__ int wsum[16];
    __shared__ int woff[16];
    int t = threadIdx.x, lane = t & 63, wid = t >> 6;
    int v = (t < nb) ? bsum[t] : 0;
    int x = v;
#pragma unroll
    for (int o = 1; o < 64; o <<= 1) {
        int tv = __shfl_up(x, o, 64);
        if (lane >= o) x += tv;
    }
    if (lane == 63) wsum[wid] = x;
    __syncthreads();
    if (wid == 0) {
        int y = (lane < 16) ? wsum[lane] : 0;
        int z = y;
#pragma unroll
        for (int o = 1; o < 16; o <<= 1) {
            int tv = __shfl_up(z, o, 64);
            if (lane >= o) z += tv;
        }
        if (lane < 16) woff[lane] = z - y;
    }
    __syncthreads();
    if (t < nb) boff[t] = woff[wid] + x - v;
}

// phase 3: per-element exclusive positions -> rowstart & cursor
__global__ __launch_bounds__(256) void k_scan3(const int* __restrict__ deg,
                                               const int* __restrict__ boff,
                                               int* __restrict__ rowstart,
                                               int* __restrict__ cursor, int N,
                                               int Etot) {
    int t = threadIdx.x, lane = t & 63, wid = t >> 6;
    int base = blockIdx.x * 1024 + t * 4;
    int v0 = 0, v1 = 0, v2 = 0, v3 = 0;
    if (base + 3 < N) {
        int4 v = *(const int4*)&deg[base];
        v0 = v.x; v1 = v.y; v2 = v.z; v3 = v.w;
    } else {
        if (base + 0 < N) v0 = deg[base + 0];
        if (base + 1 < N) v1 = deg[base + 1];
        if (base + 2 < N) v2 = deg[base + 2];
        if (base + 3 < N) v3 = deg[base + 3];
    }
    int s4 = v0 + v1 + v2 + v3;
    int x = s4;
#pragma unroll
    for (int o = 1; o < 64; o <<= 1) {
        int tv = __shfl_up(x, o, 64);
        if (lane >= o) x += tv;
    }
    __shared__ int ws[4];
    if (lane == 63) ws[wid] = x;
    __syncthreads();
    int woff = 0;
#pragma unroll
    for (int w = 0; w < 4; w++)
        if (w < wid) woff += ws[w];
    int ex = boff[blockIdx.x] + woff + (x - s4);
    int e0 = ex, e1 = ex + v0, e2 = e1 + v1, e3 = e2 + v2;
    if (base + 0 < N) { rowstart[base + 0] = e0; cursor[base + 0] = e0; }
    if (base + 1 < N) { rowstart[base + 1] = e1; cursor[base + 1] = e1; }
    if (base + 2 < N) { rowstart[base + 2] = e2; cursor[base + 2] = e2; }
    if (base + 3 < N) { rowstart[base + 3] = e3; cursor[base + 3] = e3; }
    if (blockIdx.x == 0 && t == 0) rowstart[N] = Etot;
}

__global__ void k_fill(const int* __restrict__ src32, const int* __restrict__ dst32,
                       int* __restrict__ cursor, int* __restrict__ adj, int Etot) {
    int i = blockIdx.x * blockDim.x + threadIdx.x;
    if (i < Etot) {
        int d = dst32[i];
        int pos = atomicAdd(&cursor[d], 1);
        adj[pos] = src32[i];
    }
}

// --------------------------- prep: cvt x + transpose W1,W2 ------------------
__global__ void k_prep(const float* __restrict__ x, const float* __restrict__ W1,
                       const float* __restrict__ W2,
                       unsigned short* __restrict__ xb,
                       unsigned short* __restrict__ W1t,
                       unsigned short* __restrict__ W2t, int n8) {
    int i = blockIdx.x * blockDim.x + threadIdx.x;
    if (i < n8) {
        const float4* p = (const float4*)(x + (size_t)i * 8);
        float4 a = p[0], b = p[1];
        unsigned short r[8] = {f2bf(a.x), f2bf(a.y), f2bf(a.z), f2bf(a.w),
                               f2bf(b.x), f2bf(b.y), f2bf(b.z), f2bf(b.w)};
        *(short8*)(xb + (size_t)i * 8) = *(const short8*)r;
        return;
    }
    int i2 = i - n8;
    if (i2 < F_IN * D1) {  // W1t[n*F_IN+k] = W1[k*D1+n]
        int nn = i2 / F_IN, kk = i2 - nn * F_IN;
        W1t[i2] = f2bf(W1[(size_t)kk * D1 + nn]);
        return;
    }
    int i3 = i2 - F_IN * D1;
    if (i3 < D1 * C2) {  // W2t[n*D1+k] = W2[k*C2+n]
        int nn = i3 / D1, kk = i3 - nn * D1;
        W2t[i3] = f2bf(W2[(size_t)kk * C2 + nn]);
    }
}

// --------------------------- bf16 MFMA GEMM ---------------------------------
// C[M,NC] = A[M,K] @ Bt[NC,K]^T.  K % 64 == 0.  256 threads = 4 waves.
template <int WM, int WN, int MF, int NF, bool OUT_BF16>
__global__ __launch_bounds__(256) void k_gemm_bf16(
    const unsigned short* __restrict__ A, const unsigned short* __restrict__ Bt,
    void* __restrict__ C, int M, int K, int NC) {
    constexpr int BM = WM * MF * 16;
    constexpr int BN = WN * NF * 16;
    constexpr int BK = 64;
    constexpr int LDK = BK + 8;
    __shared__ unsigned short As[BM][LDK];
    __shared__ unsigned short Bs[BN][LDK];
    const int tid = threadIdx.x;
    const int row0 = blockIdx.x * BM, col0 = blockIdx.y * BN;
    const int wave = tid >> 6, lane = tid & 63;
    const int wr = wave / WN, wc = wave % WN;
    const int lrow = lane & 15, lkg = lane >> 4;
    f32x4 acc[MF][NF] = {};
    for (int k0 = 0; k0 < K; k0 += BK) {
        for (int i = tid; i < BM * BK / 8; i += 256) {
            int r = i >> 3, kq = (i & 7) * 8;
            short8 v = {};
            if (row0 + r < M)
                v = *(const short8*)&A[(size_t)(row0 + r) * K + k0 + kq];
            *(short8*)&As[r][kq] = v;
        }
        for (int i = tid; i < BN * BK / 8; i += 256) {
            int r = i >> 3, kq = (i & 7) * 8;
            short8 v = *(const short8*)&Bt[(size_t)(col0 + r) * K + k0 + kq];
            *(short8*)&Bs[r][kq] = v;
        }
        __syncthreads();
#pragma unroll
        for (int kk = 0; kk < BK; kk += 32) {
            short8 af[MF], bfr[NF];
#pragma unroll
            for (int m = 0; m < MF; m++)
                af[m] = *(const short8*)&As[wr * MF * 16 + m * 16 + lrow][kk + lkg * 8];
#pragma unroll
            for (int n = 0; n < NF; n++)
                bfr[n] = *(const short8*)&Bs[wc * NF * 16 + n * 16 + lrow][kk + lkg * 8];
#pragma unroll
            for (int m = 0; m < MF; m++)
#pragma unroll
                for (int n = 0; n < NF; n++)
                    acc[m][n] = __builtin_amdgcn_mfma_f32_16x16x32_bf16(
                        af[m], bfr[n], acc[m][n], 0, 0, 0);
        }
        __syncthreads();
    }
#pragma unroll
    for (int m = 0; m < MF; m++)
#pragma unroll
        for (int n = 0; n < NF; n++)
#pragma unroll
            for (int r = 0; r < 4; r++) {
                int gr = row0 + wr * MF * 16 + m * 16 + lkg * 4 + r;
                int gc = col0 + wc * NF * 16 + n * 16 + lrow;
                if (gr < M) {
                    if (OUT_BF16)
                        ((unsigned short*)C)[(size_t)gr * NC + gc] = f2bf(acc[m][n][r]);
                    else
                        ((float*)C)[(size_t)gr * NC + gc] = acc[m][n][r];
                }
            }
}

// --------------------------- attention scores -------------------------------
__global__ void k_scores1(const unsigned short* __restrict__ h1b,
                          const float* __restrict__ a_src,
                          const float* __restrict__ a_dst,
                          float* __restrict__ s_src, float* __restrict__ s_dst,
                          int N) {
    int gid = blockIdx.x * blockDim.x + threadIdx.x;
    int n = gid >> 6, lane = gid & 63;
    if (n >= N) return;
    short8 hv = *(const short8*)&h1b[(size_t)n * D1 + lane * 8];
    float h[8];
#pragma unroll
    for (int j = 0; j < 8; j++) h[j] = bf2f((unsigned short)hv[j]);
    const float4* ap = (const float4*)&a_src[lane * 8];
    float4 a0 = ap[0], a1 = ap[1];
    const float4* bp = (const float4*)&a_dst[lane * 8];
    float4 b0 = bp[0], b1v = bp[1];
    float ss = h[0] * a0.x + h[1] * a0.y + h[2] * a0.z + h[3] * a0.w +
               h[4] * a1.x + h[5] * a1.y + h[6] * a1.z + h[7] * a1.w;
    float dd = h[0] * b0.x + h[1] * b0.y + h[2] * b0.z + h[3] * b0.w +
               h[4] * b1v.x + h[5] * b1v.y + h[6] * b1v.z + h[7] * b1v.w;
#pragma unroll
    for (int o = 1; o < 16; o <<= 1) {
        ss += __shfl_xor(ss, o, 64);
        dd += __shfl_xor(dd, o, 64);
    }
    if ((lane & 15) == 0) {
        int h4 = lane >> 4;
        s_src[(size_t)n * H1 + h4] = ss;
        s_dst[(size_t)n * H1 + h4] = dd;
    }
}

__global__ void k_scores2(const float* __restrict__ h2lin,
                          const float* __restrict__ a_src,
                          const float* __restrict__ a_dst,
                          float* __restrict__ s_src, float* __restrict__ s_dst,
                          int N) {
    int gid = blockIdx.x * blockDim.x + threadIdx.x;
    int n = gid >> 6, lane = gid & 63;
    if (n >= N) return;
    float v = h2lin[(size_t)n * C2 + lane];
    float ss = v * a_src[lane], dd = v * a_dst[lane];
#pragma unroll
    for (int o = 1; o < 64; o <<= 1) {
        ss += __shfl_xor(ss, o, 64);
        dd += __shfl_xor(dd, o, 64);
    }
    if (lane == 0) {
        s_src[n] = ss;
        s_dst[n] = dd;
    }
}

// --------------------------- conv1 aggregate: wave per node -----------------
// Softmax: lane=(edge jj=lane>>2, head h4=lane&3), 16 edges/chunk.
// Gather: lane owns channels [8*lane, 8*lane+8), head hg=lane>>4; alpha
// recomputed per edge in-register; one bf16x8 (16B) row load per edge.
__global__ __launch_bounds__(256) void k_agg1(
    const unsigned short* __restrict__ h1b, const float* __restrict__ s_src,
    const float* __restrict__ s_dst, const int* __restrict__ rowstart,
    const int* __restrict__ adj, const float* __restrict__ b1,
    unsigned short* __restrict__ out1, int N) {
    int wv = (blockIdx.x * blockDim.x + threadIdx.x) >> 6;
    if (wv >= N) return;
    int lane = threadIdx.x & 63;
    int beg = rowstart[wv], end = rowstart[wv + 1];
    int h4 = lane & 3, jj = lane >> 2;
    float sdh = s_dst[(size_t)wv * 4 + h4];
    // max
    float m = -1e30f;
    for (int c0 = beg; c0 < end; c0 += 16) {
        int j = c0 + jj;
        if (j < end) {
            int sj = adj[j];
            float e = LRELU(s_src[(size_t)sj * 4 + h4] + sdh);
            m = fmaxf(m, e);
        }
    }
#pragma unroll
    for (int o = 4; o < 64; o <<= 1) m = fmaxf(m, __shfl_xor(m, o, 64));
    // denom
    float dn = 0.f;
    for (int c0 = beg; c0 < end; c0 += 16) {
        int j = c0 + jj;
        if (j < end) {
            int sj = adj[j];
            float e = LRELU(s_src[(size_t)sj * 4 + h4] + sdh);
            dn += __expf(e - m);
        }
    }
#pragma unroll
    for (int o = 4; o < 64; o <<= 1) dn += __shfl_xor(dn, o, 64);
    float inv = 1.f / (dn + 1e-16f);
    // broadcast per-gather-head stats (lane hg holds h4==hg for hg<4)
    int hg = lane >> 4;
    float mg = __shfl(m, hg, 64);
    float invg = __shfl(inv, hg, 64);
    float sdg = __shfl(sdh, hg, 64);
    // gather
    float acc[8] = {};
    for (int j = beg; j < end; ++j) {
        int sj = adj[j];
        float e = LRELU(s_src[(size_t)sj * 4 + hg] + sdg);
        float a = __expf(e - mg) * invg;
        short8 v = *(const short8*)&h1b[(size_t)sj * D1 + lane * 8];
#pragma unroll
        for (int i = 0; i < 8; i++) acc[i] += a * bf2f((unsigned short)v[i]);
    }
    const float4* bp = (const float4*)&b1[lane * 8];
    float4 bb0 = bp[0], bb1 = bp[1];
    float r[8];
    r[0] = acc[0] + bb0.x; r[1] = acc[1] + bb0.y;
    r[2] = acc[2] + bb0.z; r[3] = acc[3] + bb0.w;
    r[4] = acc[4] + bb1.x; r[5] = acc[5] + bb1.y;
    r[6] = acc[6] + bb1.z; r[7] = acc[7] + bb1.w;
    unsigned short o16[8];
#pragma unroll
    for (int i = 0; i < 8; i++) {
        float z = r[i] > 0.f ? r[i] : expm1f(r[i]);
        o16[i] = f2bf(z);
    }
    *(short8*)&out1[(size_t)wv * D1 + lane * 8] = *(const short8*)o16;
}

// --------------------------- conv2 aggregate: wave per node -----------------
// Softmax: lane=edge (64/chunk). Gather: 4 edges x 16 lanes x float4.
__global__ __launch_bounds__(256) void k_agg2(
    const float* __restrict__ h2lin, const float* __restrict__ s_src,
    const float* __restrict__ s_dst, const int* __restrict__ rowstart,
    const int* __restrict__ adj, const float* __restrict__ b2,
    float* __restrict__ h2, int N) {
    int wv = (blockIdx.x * blockDim.x + threadIdx.x) >> 6;
    if (wv >= N) return;
    int lane = threadIdx.x & 63;
    int beg = rowstart[wv], end = rowstart[wv + 1];
    float sd = s_dst[wv];
    float m = -1e30f;
    for (int c0 = beg; c0 < end; c0 += 64) {
        int j = c0 + lane;
        if (j < end) m = fmaxf(m, LRELU(s_src[adj[j]] + sd));
    }
#pragma unroll
    for (int o = 1; o < 64; o <<= 1) m = fmaxf(m, __shfl_xor(m, o, 64));
    float dn = 0.f;
    for (int c0 = beg; c0 < end; c0 += 64) {
        int j = c0 + lane;
        if (j < end) dn += __expf(LRELU(s_src[adj[j]] + sd) - m);
    }
#pragma unroll
    for (int o = 1; o < 64; o <<= 1) dn += __shfl_xor(dn, o, 64);
    float inv = 1.f / (dn + 1e-16f);
    int eg = lane >> 4, ch = (lane & 15) * 4;
    float a0 = 0.f, a1 = 0.f, a2 = 0.f, a3 = 0.f;
    for (int j0 = beg; j0 < end; j0 += 4) {
        int j = j0 + eg;
        if (j < end) {
            int sj = adj[j];
            float a = __expf(LRELU(s_src[sj] + sd) - m) * inv;
            float4 r = *(const float4*)&h2lin[(size_t)sj * C2 + ch];
            a0 += a * r.x; a1 += a * r.y; a2 += a * r.z; a3 += a * r.w;
        }
    }
#pragma unroll
    for (int o = 16; o < 64; o <<= 1) {
        a0 += __shfl_xor(a0, o, 64);
        a1 += __shfl_xor(a1, o, 64);
        a2 += __shfl_xor(a2, o, 64);
        a3 += __shfl_xor(a3, o, 64);
    }
    if (lane < 16) {
        const float4 bb = *(const float4*)&b2[ch];
        float r0 = a0 + bb.x, r1 = a1 + bb.y, r2 = a2 + bb.z, r3 = a3 + bb.w;
        r0 = r0 > 0.f ? r0 : expm1f(r0);
        r1 = r1 > 0.f ? r1 : expm1f(r1);
        r2 = r2 > 0.f ? r2 : expm1f(r2);
        r3 = r3 > 0.f ? r3 : expm1f(r3);
        *(float4*)&h2[(size_t)wv * C2 + ch] = make_float4(r0, r1, r2, r3);
    }
}

// --------------------------- MLP + LN + out ---------------------------------
__global__ __launch_bounds__(256) void k_mlp(
    const float* __restrict__ h2, const float* __restrict__ Wm1,
    const float* __restrict__ bm1, const float* __restrict__ g_ln,
    const float* __restrict__ b_ln, const float* __restrict__ Wm2,
    const float* __restrict__ bm2, float* __restrict__ out, int N) {
    __shared__ float w1[C2 * DM1];
    __shared__ float w2[DM1 * DM2];
    __shared__ float cb1[DM1], cg[DM1], cbl[DM1], cb2[DM2];
    int tid = threadIdx.x;
    for (int i = tid; i < C2 * DM1; i += 256) w1[i] = Wm1[i];
    for (int i = tid; i < DM1 * DM2; i += 256) w2[i] = Wm2[i];
    if (tid < DM1) {
        cb1[tid] = bm1[tid];
        cg[tid] = g_ln[tid];
        cbl[tid] = b_ln[tid];
    } else if (tid < DM1 + DM2) {
        cb2[tid - DM1] = bm2[tid - DM1];
    }
    __syncthreads();
    int n = blockIdx.x * 256 + tid;
    if (n >= N) return;
    float h[C2];
    const float4* hp = (const float4*)&h2[(size_t)n * C2];
#pragma unroll
    for (int i = 0; i < C2 / 4; i++) {
        float4 v = hp[i];
        h[4 * i] = v.x; h[4 * i + 1] = v.y;
        h[4 * i + 2] = v.z; h[4 * i + 3] = v.w;
    }
    float t[DM1];
#pragma unroll
    for (int j = 0; j < DM1; j++) {
        float a = cb1[j];
#pragma unroll
        for (int c = 0; c < C2; c++) a += h[c] * w1[c * DM1 + j];
        t[j] = a;
    }
    float mu = 0.f;
#pragma unroll
    for (int j = 0; j < DM1; j++) mu += t[j];
    mu *= (1.f / DM1);
    float var = 0.f;
#pragma unroll
    for (int j = 0; j < DM1; j++) {
        float d = t[j] - mu;
        var += d * d;
    }
    var *= (1.f / DM1);
    float rs = rsqrtf(var + 1e-5f);
#pragma unroll
    for (int j = 0; j < DM1; j++) {
        float z = (t[j] - mu) * rs * cg[j] + cbl[j];
        t[j] = z > 0.f ? z : 0.f;
    }
    float o[DM2];
#pragma unroll
    for (int k = 0; k < DM2; k++) {
        float a = cb2[k];
#pragma unroll
        for (int j = 0; j < DM1; j++) a += t[j] * w2[j * DM2 + k];
        o[k] = a;
    }
    float4* op = (float4*)&out[(size_t)n * DM2];
    op[0] = make_float4(o[0], o[1], o[2], o[3]);
    op[1] = make_float4(o[4], o[5], o[6], o[7]);
    op[2] = make_float4(o[8], o[9], o[10], o[11]);
    op[3] = make_float4(o[12], o[13], o[14], o[15]);
}

// ---------------------------------------------------------------------------
extern "C" void kernel_launch(void* const* d_in, const int* in_sizes, int n_in,
                              void* d_out, int out_size, void* d_ws,
                              size_t ws_size, hipStream_t stream) {
    const float* x      = (const float*)d_in[0];
    const void*  ei     = d_in[1];
    const float* W1     = (const float*)d_in[3];
    const float* a_src1 = (const float*)d_in[4];
    const float* a_dst1 = (const float*)d_in[5];
    const float* b1     = (const float*)d_in[6];
    const float* W2     = (const float*)d_in[7];
    const float* a_src2 = (const float*)d_in[8];
    const float* a_dst2 = (const float*)d_in[9];
    const float* b2     = (const float*)d_in[10];
    const float* Wm1    = (const float*)d_in[11];
    const float* bm1    = (const float*)d_in[12];
    const float* g_ln   = (const float*)d_in[13];
    const float* b_ln   = (const float*)d_in[14];
    const float* Wm2    = (const float*)d_in[15];
    const float* bm2    = (const float*)d_in[16];

    const int N    = in_sizes[0] / F_IN;
    const int E    = in_sizes[1] / 2;
    const int Etot = E + N;
    const int nb   = (N + 1023) / 1024;

    char* ws = (char*)d_ws;
    size_t off = 0;
    auto alloc = [&](size_t bytes) {
        size_t o = off;
        off += (bytes + 255) & ~(size_t)255;
        return o;
    };
    int*   flag     = (int*)(ws + alloc(4));
    int*   src32    = (int*)(ws + alloc((size_t)Etot * 4));
    int*   dst32    = (int*)(ws + alloc((size_t)Etot * 4));
    int*   deg      = (int*)(ws + alloc((size_t)N * 4));
    int*   bsum     = (int*)(ws + alloc(4096 * 4));
    int*   boff     = (int*)(ws + alloc(4096 * 4));
    int*   rowstart = (int*)(ws + alloc((size_t)(N + 1) * 4));
    int*   cursor   = (int*)(ws + alloc((size_t)N * 4));
    int*   adj      = (int*)(ws + alloc((size_t)Etot * 4));
    float* s_src1   = (float*)(ws + alloc((size_t)N * H1 * 4));
    float* s_dst1   = (float*)(ws + alloc((size_t)N * H1 * 4));
    unsigned short* xb   = (unsigned short*)(ws + alloc((size_t)N * F_IN * 2));
    unsigned short* W1t  = (unsigned short*)(ws + alloc((size_t)F_IN * D1 * 2));
    unsigned short* W2t  = (unsigned short*)(ws + alloc((size_t)D1 * C2 * 2));
    unsigned short* h1b  = (unsigned short*)(ws + alloc((size_t)N * D1 * 2));
    unsigned short* out1 = (unsigned short*)(ws + alloc((size_t)N * D1 * 2));
    float* h2lin = (float*)(ws + alloc((size_t)N * C2 * 4));
    float* h2    = (float*)(ws + alloc((size_t)N * C2 * 4));
    float* s_src2 = s_src1;
    float* s_dst2 = s_dst1;

    hipMemsetAsync(deg, 0, (size_t)N * 4, stream);
    k_detect<<<1, 256, 0, stream>>>(ei, E, flag);
    k_convert<<<(Etot + 255) / 256, 256, 0, stream>>>(ei, flag, E, N, src32, dst32, deg);
    k_scan1<<<nb, 256, 0, stream>>>(deg, bsum, N);
    k_scan2<<<1, 1024, 0, stream>>>(bsum, boff, nb);
    k_scan3<<<nb, 256, 0, stream>>>(deg, boff, rowstart, cursor, N, Etot);
    k_fill<<<(Etot + 255) / 256, 256, 0, stream>>>(src32, dst32, cursor, adj, Etot);

    // prep: x->bf16, W1/W2 -> bf16 transposed
    int n8 = N * F_IN / 8;
    int prep_items = n8 + F_IN * D1 + D1 * C2;
    k_prep<<<(prep_items + 255) / 256, 256, 0, stream>>>(x, W1, W2, xb, W1t, W2t, n8);

    // conv1
    k_gemm_bf16<2, 2, 4, 4, true>
        <<<dim3((N + 127) / 128, D1 / 128), 256, 0, stream>>>(xb, W1t, h1b, N, F_IN, D1);
    k_scores1<<<((size_t)N * 64 + 255) / 256, 256, 0, stream>>>(h1b, a_src1, a_dst1,
                                                                s_src1, s_dst1, N);
    k_agg1<<<(N * 64 + 255) / 256, 256, 0, stream>>>(h1b, s_src1, s_dst1, rowstart,
                                                     adj, b1, out1, N);

    // conv2
    k_gemm_bf16<4, 1, 2, 4, false>
        <<<dim3((N + 127) / 128, 1), 256, 0, stream>>>(out1, W2t, h2lin, N, D1, C2);
    k_scores2<<<((size_t)N * 64 + 255) / 256, 256, 0, stream>>>(h2lin, a_src2, a_dst2,
                                                                s_src2, s_dst2, N);
    k_agg2<<<(N * 64 + 255) / 256, 256, 0, stream>>>(h2lin, s_src2, s_dst2, rowstart,
                                                     adj, b2, h2, N);

    // MLP head
    k_mlp<<<(N + 255) / 256, 256, 0, stream>>>(h2, Wm1, bm1, g_ln, b_ln, Wm2, bm2,
                                               (float*)d_out, N);
}

// Round 7
// 352.861 us; speedup vs baseline: 2.1207x; 1.0620x over previous
//
#include <hip/hip_runtime.h>
#include <cmath>

// ---------------------------------------------------------------------------
// SpectralGAT: 2-layer GAT (H1=4,C1=128 concat -> 512; H=1,C2=64) + MLP.
// bf16 MFMA GEMMs with global_load_lds staging (swizzled source + swizzled
// ds_read, linear LDS dest); attention scores fused into GEMM epilogues;
// wave-per-node aggregation; parallel CSR scan. CSR rebuilt every call.
// ---------------------------------------------------------------------------

#define F_IN 128
#define H1   4
#define C1   128
#define D1   512   // H1*C1
#define C2   64
#define DM1  32
#define DM2  16

#define LRELU(x) ((x) > 0.f ? (x) : 0.2f * (x))

typedef float f32x4 __attribute__((ext_vector_type(4)));
typedef short short8 __attribute__((ext_vector_type(8)));

static __device__ __forceinline__ float bf2f(unsigned short u) {
    return __builtin_bit_cast(float, (unsigned)u << 16);
}
static __device__ __forceinline__ unsigned short f2bf(float f) {
    unsigned u = __builtin_bit_cast(unsigned, f);
    u = (u + 0x7fffu + ((u >> 16) & 1u)) >> 16;
    return (unsigned short)u;
}

// --------------------------- edge dtype detect ------------------------------
__global__ void k_detect(const void* ei, int E, int* flag) {
    __shared__ int any;
    if (threadIdx.x == 0) any = 0;
    __syncthreads();
    const int* p = (const int*)ei;
    int cnt = E < 4096 ? E : 4096;
    int stride = E / cnt;
    int local = 0;
    for (int i = threadIdx.x; i < cnt; i += blockDim.x) {
        long long idx = (long long)i * stride;
        local |= p[2 * idx + 1];
    }
    if (local) atomicOr(&any, 1);
    __syncthreads();
    if (threadIdx.x == 0) *flag = (any == 0) ? 1 : 0;
}

// convert edge_index -> int32 src/dst (+self-loops) and count degrees
__global__ void k_convert(const void* ei, const int* flag, int E, int N,
                          int* src32, int* dst32, int* deg) {
    int i = blockIdx.x * blockDim.x + threadIdx.x;
    int Etot = E + N;
    if (i >= Etot) return;
    int s, d;
    if (i < E) {
        if (*flag) {
            const long long* q = (const long long*)ei;
            s = (int)q[i];
            d = (int)q[(size_t)E + i];
        } else {
            const int* q = (const int*)ei;
            s = q[i];
            d = q[(size_t)E + i];
        }
    } else {
        s = i - E;
        d = i - E;
    }
    src32[i] = s;
    dst32[i] = d;
    atomicAdd(&deg[d], 1);
}

// --------------------------- parallel scan (3 phases) -----------------------
__global__ __launch_bounds__(256) void k_scan1(const int* __restrict__ deg,
                                               int* __restrict__ bsum, int N) {
    int t = threadIdx.x;
    int base = blockIdx.x * 1024 + t * 4;
    int s = 0;
    if (base + 3 < N) {
        int4 v = *(const int4*)&deg[base];
        s = v.x + v.y + v.z + v.w;
    } else {
        for (int k = 0; k < 4; k++)
            if (base + k < N) s += deg[base + k];
    }
#pragma unroll
    for (int o = 1; o < 64; o <<= 1) s += __shfl_xor(s, o, 64);
    __shared__ int ws[4];
    if ((t & 63) == 0) ws[t >> 6] = s;
    __syncthreads();
    if (t == 0) bsum[blockIdx.x] = ws[0] + ws[1] + ws[2] + ws[3];
}

__global__ __launch_bounds__(1024) void k_scan2(const int* __restrict__ bsum,
                                                int* __restrict__ boff, int nb) {
    __shared__ int wsum[16];
    __shared__ int woff[16];
    int t = threadIdx.x, lane = t & 63, wid = t >> 6;
    int v = (t < nb) ? bsum[t] : 0;
    int x = v;
#pragma unroll
    for (int o = 1; o < 64; o <<= 1) {
        int tv = __shfl_up(x, o, 64);
        if (lane >= o) x += tv;
    }
    if (lane == 63) wsum[wid] = x;
    __syncthreads();
    if (wid == 0) {
        int y = (lane < 16) ? wsum[lane] : 0;
        int z = y;
#pragma unroll
        for (int o = 1; o < 16; o <<= 1) {
            int tv = __shfl_up(z, o, 64);
            if (lane >= o) z += tv;
        }
        if (lane < 16) woff[lane] = z - y;
    }
    __syncthreads();
    if (t < nb) boff[t] = woff[wid] + x - v;
}

__global__ __launch_bounds__(256) void k_scan3(const int* __restrict__ deg,
                                               const int* __restrict__ boff,
                                               int* __restrict__ rowstart,
                                               int* __restrict__ cursor, int N,
                                               int Etot) {
    int t = threadIdx.x, lane = t & 63, wid = t >> 6;
    int base = blockIdx.x * 1024 + t * 4;
    int v0 = 0, v1 = 0, v2 = 0, v3 = 0;
    if (base + 3 < N) {
        int4 v = *(const int4*)&deg[base];
        v0 = v.x; v1 = v.y; v2 = v.z; v3 = v.w;
    } else {
        if (base + 0 < N) v0 = deg[base + 0];
        if (base + 1 < N) v1 = deg[base + 1];
        if (base + 2 < N) v2 = deg[base + 2];
        if (base + 3 < N) v3 = deg[base + 3];
    }
    int s4 = v0 + v1 + v2 + v3;
    int x = s4;
#pragma unroll
    for (int o = 1; o < 64; o <<= 1) {
        int tv = __shfl_up(x, o, 64);
        if (lane >= o) x += tv;
    }
    __shared__ int ws[4];
    if (lane == 63) ws[wid] = x;
    __syncthreads();
    int woff = 0;
#pragma unroll
    for (int w = 0; w < 4; w++)
        if (w < wid) woff += ws[w];
    int ex = boff[blockIdx.x] + woff + (x - s4);
    int e0 = ex, e1 = ex + v0, e2 = e1 + v1, e3 = e2 + v2;
    if (base + 0 < N) { rowstart[base + 0] = e0; cursor[base + 0] = e0; }
    if (base + 1 < N) { rowstart[base + 1] = e1; cursor[base + 1] = e1; }
    if (base + 2 < N) { rowstart[base + 2] = e2; cursor[base + 2] = e2; }
    if (base + 3 < N) { rowstart[base + 3] = e3; cursor[base + 3] = e3; }
    if (blockIdx.x == 0 && t == 0) rowstart[N] = Etot;
}

__global__ void k_fill(const int* __restrict__ src32, const int* __restrict__ dst32,
                       int* __restrict__ cursor, int* __restrict__ adj, int Etot) {
    int i = blockIdx.x * blockDim.x + threadIdx.x;
    if (i < Etot) {
        int d = dst32[i];
        int pos = atomicAdd(&cursor[d], 1);
        adj[pos] = src32[i];
    }
}

// --------------------------- prep: cvt x + transpose W1,W2 ------------------
__global__ void k_prep(const float* __restrict__ x, const float* __restrict__ W1,
                       const float* __restrict__ W2,
                       unsigned short* __restrict__ xb,
                       unsigned short* __restrict__ W1t,
                       unsigned short* __restrict__ W2t, int n8) {
    int i = blockIdx.x * blockDim.x + threadIdx.x;
    if (i < n8) {
        const float4* p = (const float4*)(x + (size_t)i * 8);
        float4 a = p[0], b = p[1];
        unsigned short r[8] = {f2bf(a.x), f2bf(a.y), f2bf(a.z), f2bf(a.w),
                               f2bf(b.x), f2bf(b.y), f2bf(b.z), f2bf(b.w)};
        *(short8*)(xb + (size_t)i * 8) = *(const short8*)r;
        return;
    }
    int i2 = i - n8;
    if (i2 < F_IN * D1) {  // W1t[n*F_IN+k] = W1[k*D1+n]
        int nn = i2 / F_IN, kk = i2 - nn * F_IN;
        W1t[i2] = f2bf(W1[(size_t)kk * D1 + nn]);
        return;
    }
    int i3 = i2 - F_IN * D1;
    if (i3 < D1 * C2) {  // W2t[n*D1+k] = W2[k*C2+n]
        int nn = i3 / D1, kk = i3 - nn * D1;
        W2t[i3] = f2bf(W2[(size_t)kk * C2 + nn]);
    }
}

// --------------------------- bf16 MFMA GEMM (+fused scores) -----------------
// C[M,NC] = A[M,K] @ Bt[NC,K]^T.  K % 64 == 0.  256 threads = 4 waves.
// Staging: global_load_lds width=16, linear LDS dest, source pre-swizzled so
// ds_read applies unit ^= (row&7)  (rule-21 both-sides swizzle).
// SC_MODE: 0=none, 1=per-head scores (s[gr*H1+blockIdx.y], a-vec flat[gc]),
//          2=full-row scores (s[gr]).
template <int WM, int WN, int MF, int NF, bool OUT_BF16, int SC_MODE>
__global__ __launch_bounds__(256) void k_gemm_bf16(
    const unsigned short* __restrict__ A, const unsigned short* __restrict__ Bt,
    void* __restrict__ C, int M, int K, int NC,
    const float* __restrict__ avs, const float* __restrict__ avd,
    float* __restrict__ s_src, float* __restrict__ s_dst) {
    constexpr int BM = WM * MF * 16;
    constexpr int BN = WN * NF * 16;
    constexpr int BK = 64;  // 8 units of 16B per row
    __shared__ unsigned short As[BM * BK];
    __shared__ unsigned short Bs[BN * BK];
    __shared__ float ps_lds[WN][BM], pd_lds[WN][BM];
    const int tid = threadIdx.x;
    const int row0 = blockIdx.x * BM, col0 = blockIdx.y * BN;
    const int wave = tid >> 6, lane = tid & 63;
    const int wr = wave / WN, wc = wave % WN;
    const int lrow = lane & 15, lkg = lane >> 4;
    f32x4 acc[MF][NF] = {};
    for (int k0 = 0; k0 < K; k0 += BK) {
#pragma unroll
        for (int inst = 0; inst < (BM * 8) / 256; ++inst) {
            int ibase = inst * 256 + wave * 64;
            int i = ibase + lane;
            int r = i >> 3, u = i & 7, su = u ^ (r & 7);
            const unsigned short* gp = A + (size_t)(row0 + r) * K + k0 + su * 8;
            __builtin_amdgcn_global_load_lds(
                (const __attribute__((address_space(1))) void*)gp,
                (__attribute__((address_space(3))) void*)&As[ibase * 8], 16, 0, 0);
        }
#pragma unroll
        for (int inst = 0; inst < (BN * 8) / 256; ++inst) {
            int ibase = inst * 256 + wave * 64;
            int i = ibase + lane;
            int r = i >> 3, u = i & 7, su = u ^ (r & 7);
            const unsigned short* gp = Bt + (size_t)(col0 + r) * K + k0 + su * 8;
            __builtin_amdgcn_global_load_lds(
                (const __attribute__((address_space(1))) void*)gp,
                (__attribute__((address_space(3))) void*)&Bs[ibase * 8], 16, 0, 0);
        }
        __syncthreads();
#pragma unroll
        for (int kk = 0; kk < BK; kk += 32) {
            short8 af[MF], bfr[NF];
#pragma unroll
            for (int m = 0; m < MF; m++) {
                int ar = wr * MF * 16 + m * 16 + lrow;
                int au = kk / 8 + lkg;
                af[m] = *(const short8*)&As[(ar * 8 + (au ^ (lrow & 7))) * 8];
            }
#pragma unroll
            for (int n = 0; n < NF; n++) {
                int br = wc * NF * 16 + n * 16 + lrow;
                int au = kk / 8 + lkg;
                bfr[n] = *(const short8*)&Bs[(br * 8 + (au ^ (lrow & 7))) * 8];
            }
#pragma unroll
            for (int m = 0; m < MF; m++)
#pragma unroll
                for (int n = 0; n < NF; n++)
                    acc[m][n] = __builtin_amdgcn_mfma_f32_16x16x32_bf16(
                        af[m], bfr[n], acc[m][n], 0, 0, 0);
        }
        __syncthreads();
    }
    // C store
#pragma unroll
    for (int m = 0; m < MF; m++)
#pragma unroll
        for (int n = 0; n < NF; n++)
#pragma unroll
            for (int r = 0; r < 4; r++) {
                int gr = row0 + wr * MF * 16 + m * 16 + lkg * 4 + r;
                int gc = col0 + wc * NF * 16 + n * 16 + lrow;
                if (gr < M) {
                    if (OUT_BF16)
                        ((unsigned short*)C)[(size_t)gr * NC + gc] = f2bf(acc[m][n][r]);
                    else
                        ((float*)C)[(size_t)gr * NC + gc] = acc[m][n][r];
                }
            }
    // fused attention scores from f32 accumulators
    if (SC_MODE) {
        float asv[NF], adv[NF];
#pragma unroll
        for (int n = 0; n < NF; n++) {
            int gc = col0 + wc * NF * 16 + n * 16 + lrow;
            asv[n] = avs[gc];
            adv[n] = avd[gc];
        }
#pragma unroll
        for (int m = 0; m < MF; m++)
#pragma unroll
            for (int r = 0; r < 4; r++) {
                float ps = 0.f, pd = 0.f;
#pragma unroll
                for (int n = 0; n < NF; n++) {
                    ps += acc[m][n][r] * asv[n];
                    pd += acc[m][n][r] * adv[n];
                }
#pragma unroll
                for (int o = 1; o < 16; o <<= 1) {
                    ps += __shfl_xor(ps, o, 64);
                    pd += __shfl_xor(pd, o, 64);
                }
                if (lrow == 0) {
                    int lr = wr * MF * 16 + m * 16 + lkg * 4 + r;
                    ps_lds[wc][lr] = ps;
                    pd_lds[wc][lr] = pd;
                }
            }
        __syncthreads();
        for (int rr = tid; rr < BM; rr += 256) {
            int gr = row0 + rr;
            if (gr < M) {
                float s = 0.f, d = 0.f;
#pragma unroll
                for (int w = 0; w < WN; w++) {
                    s += ps_lds[w][rr];
                    d += pd_lds[w][rr];
                }
                if (SC_MODE == 1) {
                    s_src[(size_t)gr * H1 + blockIdx.y] = s;
                    s_dst[(size_t)gr * H1 + blockIdx.y] = d;
                } else {
                    s_src[gr] = s;
                    s_dst[gr] = d;
                }
            }
        }
    }
}

// --------------------------- conv1 aggregate: wave per node -----------------
__global__ __launch_bounds__(256) void k_agg1(
    const unsigned short* __restrict__ h1b, const float* __restrict__ s_src,
    const float* __restrict__ s_dst, const int* __restrict__ rowstart,
    const int* __restrict__ adj, const float* __restrict__ b1,
    unsigned short* __restrict__ out1, int N) {
    int wv = (blockIdx.x * blockDim.x + threadIdx.x) >> 6;
    if (wv >= N) return;
    int lane = threadIdx.x & 63;
    int beg = rowstart[wv], end = rowstart[wv + 1];
    int h4 = lane & 3, jj = lane >> 2;
    float sdh = s_dst[(size_t)wv * 4 + h4];
    float m = -1e30f;
    for (int c0 = beg; c0 < end; c0 += 16) {
        int j = c0 + jj;
        if (j < end) {
            int sj = adj[j];
            float e = LRELU(s_src[(size_t)sj * 4 + h4] + sdh);
            m = fmaxf(m, e);
        }
    }
#pragma unroll
    for (int o = 4; o < 64; o <<= 1) m = fmaxf(m, __shfl_xor(m, o, 64));
    float dn = 0.f;
    for (int c0 = beg; c0 < end; c0 += 16) {
        int j = c0 + jj;
        if (j < end) {
            int sj = adj[j];
            float e = LRELU(s_src[(size_t)sj * 4 + h4] + sdh);
            dn += __expf(e - m);
        }
    }
#pragma unroll
    for (int o = 4; o < 64; o <<= 1) dn += __shfl_xor(dn, o, 64);
    float inv = 1.f / (dn + 1e-16f);
    int hg = lane >> 4;
    float mg = __shfl(m, hg, 64);
    float invg = __shfl(inv, hg, 64);
    float sdg = __shfl(sdh, hg, 64);
    float acc[8] = {};
    for (int j = beg; j < end; ++j) {
        int sj = adj[j];
        float e = LRELU(s_src[(size_t)sj * 4 + hg] + sdg);
        float a = __expf(e - mg) * invg;
        short8 v = *(const short8*)&h1b[(size_t)sj * D1 + lane * 8];
#pragma unroll
        for (int i = 0; i < 8; i++) acc[i] += a * bf2f((unsigned short)v[i]);
    }
    const float4* bp = (const float4*)&b1[lane * 8];
    float4 bb0 = bp[0], bb1 = bp[1];
    float r[8];
    r[0] = acc[0] + bb0.x; r[1] = acc[1] + bb0.y;
    r[2] = acc[2] + bb0.z; r[3] = acc[3] + bb0.w;
    r[4] = acc[4] + bb1.x; r[5] = acc[5] + bb1.y;
    r[6] = acc[6] + bb1.z; r[7] = acc[7] + bb1.w;
    unsigned short o16[8];
#pragma unroll
    for (int i = 0; i < 8; i++) {
        float z = r[i] > 0.f ? r[i] : expm1f(r[i]);
        o16[i] = f2bf(z);
    }
    *(short8*)&out1[(size_t)wv * D1 + lane * 8] = *(const short8*)o16;
}

// --------------------------- conv2 aggregate: wave per node -----------------
__global__ __launch_bounds__(256) void k_agg2(
    const float* __restrict__ h2lin, const float* __restrict__ s_src,
    const float* __restrict__ s_dst, const int* __restrict__ rowstart,
    const int* __restrict__ adj, const float* __restrict__ b2,
    float* __restrict__ h2, int N) {
    int wv = (blockIdx.x * blockDim.x + threadIdx.x) >> 6;
    if (wv >= N) return;
    int lane = threadIdx.x & 63;
    int beg = rowstart[wv], end = rowstart[wv + 1];
    float sd = s_dst[wv];
    float m = -1e30f;
    for (int c0 = beg; c0 < end; c0 += 64) {
        int j = c0 + lane;
        if (j < end) m = fmaxf(m, LRELU(s_src[adj[j]] + sd));
    }
#pragma unroll
    for (int o = 1; o < 64; o <<= 1) m = fmaxf(m, __shfl_xor(m, o, 64));
    float dn = 0.f;
    for (int c0 = beg; c0 < end; c0 += 64) {
        int j = c0 + lane;
        if (j < end) dn += __expf(LRELU(s_src[adj[j]] + sd) - m);
    }
#pragma unroll
    for (int o = 1; o < 64; o <<= 1) dn += __shfl_xor(dn, o, 64);
    float inv = 1.f / (dn + 1e-16f);
    int eg = lane >> 4, ch = (lane & 15) * 4;
    float a0 = 0.f, a1 = 0.f, a2 = 0.f, a3 = 0.f;
    for (int j0 = beg; j0 < end; j0 += 4) {
        int j = j0 + eg;
        if (j < end) {
            int sj = adj[j];
            float a = __expf(LRELU(s_src[sj] + sd) - m) * inv;
            float4 r = *(const float4*)&h2lin[(size_t)sj * C2 + ch];
            a0 += a * r.x; a1 += a * r.y; a2 += a * r.z; a3 += a * r.w;
        }
    }
#pragma unroll
    for (int o = 16; o < 64; o <<= 1) {
        a0 += __shfl_xor(a0, o, 64);
        a1 += __shfl_xor(a1, o, 64);
        a2 += __shfl_xor(a2, o, 64);
        a3 += __shfl_xor(a3, o, 64);
    }
    if (lane < 16) {
        const float4 bb = *(const float4*)&b2[ch];
        float r0 = a0 + bb.x, r1 = a1 + bb.y, r2 = a2 + bb.z, r3 = a3 + bb.w;
        r0 = r0 > 0.f ? r0 : expm1f(r0);
        r1 = r1 > 0.f ? r1 : expm1f(r1);
        r2 = r2 > 0.f ? r2 : expm1f(r2);
        r3 = r3 > 0.f ? r3 : expm1f(r3);
        *(float4*)&h2[(size_t)wv * C2 + ch] = make_float4(r0, r1, r2, r3);
    }
}

// --------------------------- MLP + LN + out ---------------------------------
__global__ __launch_bounds__(256) void k_mlp(
    const float* __restrict__ h2, const float* __restrict__ Wm1,
    const float* __restrict__ bm1, const float* __restrict__ g_ln,
    const float* __restrict__ b_ln, const float* __restrict__ Wm2,
    const float* __restrict__ bm2, float* __restrict__ out, int N) {
    __shared__ float w1[C2 * DM1];
    __shared__ float w2[DM1 * DM2];
    __shared__ float cb1[DM1], cg[DM1], cbl[DM1], cb2[DM2];
    int tid = threadIdx.x;
    for (int i = tid; i < C2 * DM1; i += 256) w1[i] = Wm1[i];
    for (int i = tid; i < DM1 * DM2; i += 256) w2[i] = Wm2[i];
    if (tid < DM1) {
        cb1[tid] = bm1[tid];
        cg[tid] = g_ln[tid];
        cbl[tid] = b_ln[tid];
    } else if (tid < DM1 + DM2) {
        cb2[tid - DM1] = bm2[tid - DM1];
    }
    __syncthreads();
    int n = blockIdx.x * 256 + tid;
    if (n >= N) return;
    float h[C2];
    const float4* hp = (const float4*)&h2[(size_t)n * C2];
#pragma unroll
    for (int i = 0; i < C2 / 4; i++) {
        float4 v = hp[i];
        h[4 * i] = v.x; h[4 * i + 1] = v.y;
        h[4 * i + 2] = v.z; h[4 * i + 3] = v.w;
    }
    float t[DM1];
#pragma unroll
    for (int j = 0; j < DM1; j++) {
        float a = cb1[j];
#pragma unroll
        for (int c = 0; c < C2; c++) a += h[c] * w1[c * DM1 + j];
        t[j] = a;
    }
    float mu = 0.f;
#pragma unroll
    for (int j = 0; j < DM1; j++) mu += t[j];
    mu *= (1.f / DM1);
    float var = 0.f;
#pragma unroll
    for (int j = 0; j < DM1; j++) {
        float d = t[j] - mu;
        var += d * d;
    }
    var *= (1.f / DM1);
    float rs = rsqrtf(var + 1e-5f);
#pragma unroll
    for (int j = 0; j < DM1; j++) {
        float z = (t[j] - mu) * rs * cg[j] + cbl[j];
        t[j] = z > 0.f ? z : 0.f;
    }
    float o[DM2];
#pragma unroll
    for (int k = 0; k < DM2; k++) {
        float a = cb2[k];
#pragma unroll
        for (int j = 0; j < DM1; j++) a += t[j] * w2[j * DM2 + k];
        o[k] = a;
    }
    float4* op = (float4*)&out[(size_t)n * DM2];
    op[0] = make_float4(o[0], o[1], o[2], o[3]);
    op[1] = make_float4(o[4], o[5], o[6], o[7]);
    op[2] = make_float4(o[8], o[9], o[10], o[11]);
    op[3] = make_float4(o[12], o[13], o[14], o[15]);
}

// ---------------------------------------------------------------------------
extern "C" void kernel_launch(void* const* d_in, const int* in_sizes, int n_in,
                              void* d_out, int out_size, void* d_ws,
                              size_t ws_size, hipStream_t stream) {
    const float* x      = (const float*)d_in[0];
    const void*  ei     = d_in[1];
    const float* W1     = (const float*)d_in[3];
    const float* a_src1 = (const float*)d_in[4];
    const float* a_dst1 = (const float*)d_in[5];
    const float* b1     = (const float*)d_in[6];
    const float* W2     = (const float*)d_in[7];
    const float* a_src2 = (const float*)d_in[8];
    const float* a_dst2 = (const float*)d_in[9];
    const float* b2     = (const float*)d_in[10];
    const float* Wm1    = (const float*)d_in[11];
    const float* bm1    = (const float*)d_in[12];
    const float* g_ln   = (const float*)d_in[13];
    const float* b_ln   = (const float*)d_in[14];
    const float* Wm2    = (const float*)d_in[15];
    const float* bm2    = (const float*)d_in[16];

    const int N    = in_sizes[0] / F_IN;
    const int E    = in_sizes[1] / 2;
    const int Etot = E + N;
    const int nb   = (N + 1023) / 1024;

    char* ws = (char*)d_ws;
    size_t off = 0;
    auto alloc = [&](size_t bytes) {
        size_t o = off;
        off += (bytes + 255) & ~(size_t)255;
        return o;
    };
    int*   flag     = (int*)(ws + alloc(4));
    int*   src32    = (int*)(ws + alloc((size_t)Etot * 4));
    int*   dst32    = (int*)(ws + alloc((size_t)Etot * 4));
    int*   deg      = (int*)(ws + alloc((size_t)N * 4));
    int*   bsum     = (int*)(ws + alloc(4096 * 4));
    int*   boff     = (int*)(ws + alloc(4096 * 4));
    int*   rowstart = (int*)(ws + alloc((size_t)(N + 1) * 4));
    int*   cursor   = (int*)(ws + alloc((size_t)N * 4));
    int*   adj      = (int*)(ws + alloc((size_t)Etot * 4));
    float* s_src1   = (float*)(ws + alloc((size_t)N * H1 * 4));
    float* s_dst1   = (float*)(ws + alloc((size_t)N * H1 * 4));
    unsigned short* xb   = (unsigned short*)(ws + alloc((size_t)N * F_IN * 2));
    unsigned short* W1t  = (unsigned short*)(ws + alloc((size_t)F_IN * D1 * 2));
    unsigned short* W2t  = (unsigned short*)(ws + alloc((size_t)D1 * C2 * 2));
    unsigned short* h1b  = (unsigned short*)(ws + alloc((size_t)N * D1 * 2));
    unsigned short* out1 = (unsigned short*)(ws + alloc((size_t)N * D1 * 2));
    float* h2lin = (float*)(ws + alloc((size_t)N * C2 * 4));
    float* h2    = (float*)(ws + alloc((size_t)N * C2 * 4));
    float* s_src2 = s_src1;
    float* s_dst2 = s_dst1;

    hipMemsetAsync(deg, 0, (size_t)N * 4, stream);
    k_detect<<<1, 256, 0, stream>>>(ei, E, flag);
    k_convert<<<(Etot + 255) / 256, 256, 0, stream>>>(ei, flag, E, N, src32, dst32, deg);
    k_scan1<<<nb, 256, 0, stream>>>(deg, bsum, N);
    k_scan2<<<1, 1024, 0, stream>>>(bsum, boff, nb);
    k_scan3<<<nb, 256, 0, stream>>>(deg, boff, rowstart, cursor, N, Etot);
    k_fill<<<(Etot + 255) / 256, 256, 0, stream>>>(src32, dst32, cursor, adj, Etot);

    // prep: x->bf16, W1/W2 -> bf16 transposed
    int n8 = N * F_IN / 8;
    int prep_items = n8 + F_IN * D1 + D1 * C2;
    k_prep<<<(prep_items + 255) / 256, 256, 0, stream>>>(x, W1, W2, xb, W1t, W2t, n8);

    // conv1: h1 = x@W1 (scores fused: block col-range == one head)
    k_gemm_bf16<2, 2, 4, 4, true, 1>
        <<<dim3((N + 127) / 128, D1 / 128), 256, 0, stream>>>(
            xb, W1t, h1b, N, F_IN, D1, a_src1, a_dst1, s_src1, s_dst1);
    k_agg1<<<(N * 64 + 255) / 256, 256, 0, stream>>>(h1b, s_src1, s_dst1, rowstart,
                                                     adj, b1, out1, N);

    // conv2: h2lin = out1@W2 (scores fused: block col-range == full C2)
    k_gemm_bf16<4, 1, 2, 4, false, 2>
        <<<dim3((N + 127) / 128, 1), 256, 0, stream>>>(
            out1, W2t, h2lin, N, D1, C2, a_src2, a_dst2, s_src2, s_dst2);
    k_agg2<<<(N * 64 + 255) / 256, 256, 0, stream>>>(h2lin, s_src2, s_dst2, rowstart,
                                                     adj, b2, h2, N);

    // MLP head
    k_mlp<<<(N + 255) / 256, 256, 0, stream>>>(h2, Wm1, bm1, g_ln, b_ln, Wm2, bm2,
                                               (float*)d_out, N);
}

// Round 8
// 340.901 us; speedup vs baseline: 2.1951x; 1.0351x over previous
//
#include <hip/hip_runtime.h>
#include <cmath>

// ---------------------------------------------------------------------------
// SpectralGAT: 2-layer GAT (H1=4,C1=128 concat -> 512; H=1,C2=64) + MLP.
// bf16 MFMA GEMMs (global_load_lds staging, both-sides swizzle); scores fused
// into GEMM epilogues; wave-per-node aggregation with chunked shfl-alpha and
// 4x-unrolled gather; h2lin bf16; parallel CSR scan rebuilt every call.
// ---------------------------------------------------------------------------

#define F_IN 128
#define H1   4
#define C1   128
#define D1   512   // H1*C1
#define C2   64
#define DM1  32
#define DM2  16

#define LRELU(x) ((x) > 0.f ? (x) : 0.2f * (x))

typedef float f32x4 __attribute__((ext_vector_type(4)));
typedef short short8 __attribute__((ext_vector_type(8)));

static __device__ __forceinline__ float bf2f(unsigned short u) {
    return __builtin_bit_cast(float, (unsigned)u << 16);
}
static __device__ __forceinline__ unsigned short f2bf(float f) {
    unsigned u = __builtin_bit_cast(unsigned, f);
    u = (u + 0x7fffu + ((u >> 16) & 1u)) >> 16;
    return (unsigned short)u;
}
static __device__ __forceinline__ float bflo(unsigned d) {
    return __builtin_bit_cast(float, d << 16);
}
static __device__ __forceinline__ float bfhi(unsigned d) {
    return __builtin_bit_cast(float, d & 0xffff0000u);
}

// --------------------------- edge dtype detect ------------------------------
__global__ void k_detect(const void* ei, int E, int* flag) {
    __shared__ int any;
    if (threadIdx.x == 0) any = 0;
    __syncthreads();
    const int* p = (const int*)ei;
    int cnt = E < 4096 ? E : 4096;
    int stride = E / cnt;
    int local = 0;
    for (int i = threadIdx.x; i < cnt; i += blockDim.x) {
        long long idx = (long long)i * stride;
        local |= p[2 * idx + 1];
    }
    if (local) atomicOr(&any, 1);
    __syncthreads();
    if (threadIdx.x == 0) *flag = (any == 0) ? 1 : 0;
}

// fused: edge convert (+self-loops, degree count) AND x/W1/W2 bf16 prep
__global__ void k_convert_prep(const void* ei, const int* flag, int E, int N,
                               int* src32, int* dst32, int* deg,
                               const float* __restrict__ x,
                               const float* __restrict__ W1,
                               const float* __restrict__ W2,
                               unsigned short* __restrict__ xb,
                               unsigned short* __restrict__ W1t,
                               unsigned short* __restrict__ W2t, int n8) {
    int i = blockIdx.x * blockDim.x + threadIdx.x;
    int Etot = E + N;
    if (i < Etot) {
        int s, d;
        if (i < E) {
            if (*flag) {
                const long long* q = (const long long*)ei;
                s = (int)q[i];
                d = (int)q[(size_t)E + i];
            } else {
                const int* q = (const int*)ei;
                s = q[i];
                d = q[(size_t)E + i];
            }
        } else {
            s = i - E;
            d = i - E;
        }
        src32[i] = s;
        dst32[i] = d;
        atomicAdd(&deg[d], 1);
        return;
    }
    int i1 = i - Etot;
    if (i1 < n8) {
        const float4* p = (const float4*)(x + (size_t)i1 * 8);
        float4 a = p[0], b = p[1];
        unsigned short r[8] = {f2bf(a.x), f2bf(a.y), f2bf(a.z), f2bf(a.w),
                               f2bf(b.x), f2bf(b.y), f2bf(b.z), f2bf(b.w)};
        *(short8*)(xb + (size_t)i1 * 8) = *(const short8*)r;
        return;
    }
    int i2 = i1 - n8;
    if (i2 < F_IN * D1) {  // W1t[n*F_IN+k] = W1[k*D1+n]
        int nn = i2 / F_IN, kk = i2 - nn * F_IN;
        W1t[i2] = f2bf(W1[(size_t)kk * D1 + nn]);
        return;
    }
    int i3 = i2 - F_IN * D1;
    if (i3 < D1 * C2) {  // W2t[n*D1+k] = W2[k*C2+n]
        int nn = i3 / D1, kk = i3 - nn * D1;
        W2t[i3] = f2bf(W2[(size_t)kk * C2 + nn]);
    }
}

// --------------------------- parallel scan (3 phases) -----------------------
__global__ __launch_bounds__(256) void k_scan1(const int* __restrict__ deg,
                                               int* __restrict__ bsum, int N) {
    int t = threadIdx.x;
    int base = blockIdx.x * 1024 + t * 4;
    int s = 0;
    if (base + 3 < N) {
        int4 v = *(const int4*)&deg[base];
        s = v.x + v.y + v.z + v.w;
    } else {
        for (int k = 0; k < 4; k++)
            if (base + k < N) s += deg[base + k];
    }
#pragma unroll
    for (int o = 1; o < 64; o <<= 1) s += __shfl_xor(s, o, 64);
    __shared__ int ws[4];
    if ((t & 63) == 0) ws[t >> 6] = s;
    __syncthreads();
    if (t == 0) bsum[blockIdx.x] = ws[0] + ws[1] + ws[2] + ws[3];
}

__global__ __launch_bounds__(1024) void k_scan2(const int* __restrict__ bsum,
                                                int* __restrict__ boff, int nb) {
    __shared__ int wsum[16];
    __shared__ int woff[16];
    int t = threadIdx.x, lane = t & 63, wid = t >> 6;
    int v = (t < nb) ? bsum[t] : 0;
    int x = v;
#pragma unroll
    for (int o = 1; o < 64; o <<= 1) {
        int tv = __shfl_up(x, o, 64);
        if (lane >= o) x += tv;
    }
    if (lane == 63) wsum[wid] = x;
    __syncthreads();
    if (wid == 0) {
        int y = (lane < 16) ? wsum[lane] : 0;
        int z = y;
#pragma unroll
        for (int o = 1; o < 16; o <<= 1) {
            int tv = __shfl_up(z, o, 64);
            if (lane >= o) z += tv;
        }
        if (lane < 16) woff[lane] = z - y;
    }
    __syncthreads();
    if (t < nb) boff[t] = woff[wid] + x - v;
}

__global__ __launch_bounds__(256) void k_scan3(const int* __restrict__ deg,
                                               const int* __restrict__ boff,
                                               int* __restrict__ rowstart,
                                               int* __restrict__ cursor, int N,
                                               int Etot) {
    int t = threadIdx.x, lane = t & 63, wid = t >> 6;
    int base = blockIdx.x * 1024 + t * 4;
    int v0 = 0, v1 = 0, v2 = 0, v3 = 0;
    if (base + 3 < N) {
        int4 v = *(const int4*)&deg[base];
        v0 = v.x; v1 = v.y; v2 = v.z; v3 = v.w;
    } else {
        if (base + 0 < N) v0 = deg[base + 0];
        if (base + 1 < N) v1 = deg[base + 1];
        if (base + 2 < N) v2 = deg[base + 2];
        if (base + 3 < N) v3 = deg[base + 3];
    }
    int s4 = v0 + v1 + v2 + v3;
    int x = s4;
#pragma unroll
    for (int o = 1; o < 64; o <<= 1) {
        int tv = __shfl_up(x, o, 64);
        if (lane >= o) x += tv;
    }
    __shared__ int ws[4];
    if (lane == 63) ws[wid] = x;
    __syncthreads();
    int woff = 0;
#pragma unroll
    for (int w = 0; w < 4; w++)
        if (w < wid) woff += ws[w];
    int ex = boff[blockIdx.x] + woff + (x - s4);
    int e0 = ex, e1 = ex + v0, e2 = e1 + v1, e3 = e2 + v2;
    if (base + 0 < N) { rowstart[base + 0] = e0; cursor[base + 0] = e0; }
    if (base + 1 < N) { rowstart[base + 1] = e1; cursor[base + 1] = e1; }
    if (base + 2 < N) { rowstart[base + 2] = e2; cursor[base + 2] = e2; }
    if (base + 3 < N) { rowstart[base + 3] = e3; cursor[base + 3] = e3; }
    if (blockIdx.x == 0 && t == 0) rowstart[N] = Etot;
}

__global__ void k_fill(const int* __restrict__ src32, const int* __restrict__ dst32,
                       int* __restrict__ cursor, int* __restrict__ adj, int Etot) {
    int i = blockIdx.x * blockDim.x + threadIdx.x;
    if (i < Etot) {
        int d = dst32[i];
        int pos = atomicAdd(&cursor[d], 1);
        adj[pos] = src32[i];
    }
}

// --------------------------- bf16 MFMA GEMM (+fused scores) -----------------
// C[M,NC] = A[M,K] @ Bt[NC,K]^T.  K % 64 == 0.  256 threads = 4 waves.
// Staging: global_load_lds width=16, linear LDS dest, source pre-swizzled so
// ds_read applies unit ^= (row&7)  (rule-21 both-sides swizzle).
// SC_MODE: 0=none, 1=per-head scores (s[gr*H1+blockIdx.y], a-vec flat[gc]),
//          2=full-row scores (s[gr]).
template <int WM, int WN, int MF, int NF, bool OUT_BF16, int SC_MODE>
__global__ __launch_bounds__(256) void k_gemm_bf16(
    const unsigned short* __restrict__ A, const unsigned short* __restrict__ Bt,
    void* __restrict__ C, int M, int K, int NC,
    const float* __restrict__ avs, const float* __restrict__ avd,
    float* __restrict__ s_src, float* __restrict__ s_dst) {
    constexpr int BM = WM * MF * 16;
    constexpr int BN = WN * NF * 16;
    constexpr int BK = 64;  // 8 units of 16B per row
    __shared__ unsigned short As[BM * BK];
    __shared__ unsigned short Bs[BN * BK];
    __shared__ float ps_lds[WN][BM], pd_lds[WN][BM];
    const int tid = threadIdx.x;
    const int row0 = blockIdx.x * BM, col0 = blockIdx.y * BN;
    const int wave = tid >> 6, lane = tid & 63;
    const int wr = wave / WN, wc = wave % WN;
    const int lrow = lane & 15, lkg = lane >> 4;
    f32x4 acc[MF][NF] = {};
    for (int k0 = 0; k0 < K; k0 += BK) {
#pragma unroll
        for (int inst = 0; inst < (BM * 8) / 256; ++inst) {
            int ibase = inst * 256 + wave * 64;
            int i = ibase + lane;
            int r = i >> 3, u = i & 7, su = u ^ (r & 7);
            const unsigned short* gp = A + (size_t)(row0 + r) * K + k0 + su * 8;
            __builtin_amdgcn_global_load_lds(
                (const __attribute__((address_space(1))) void*)gp,
                (__attribute__((address_space(3))) void*)&As[ibase * 8], 16, 0, 0);
        }
#pragma unroll
        for (int inst = 0; inst < (BN * 8) / 256; ++inst) {
            int ibase = inst * 256 + wave * 64;
            int i = ibase + lane;
            int r = i >> 3, u = i & 7, su = u ^ (r & 7);
            const unsigned short* gp = Bt + (size_t)(col0 + r) * K + k0 + su * 8;
            __builtin_amdgcn_global_load_lds(
                (const __attribute__((address_space(1))) void*)gp,
                (__attribute__((address_space(3))) void*)&Bs[ibase * 8], 16, 0, 0);
        }
        __syncthreads();
#pragma unroll
        for (int kk = 0; kk < BK; kk += 32) {
            short8 af[MF], bfr[NF];
#pragma unroll
            for (int m = 0; m < MF; m++) {
                int ar = wr * MF * 16 + m * 16 + lrow;
                int au = kk / 8 + lkg;
                af[m] = *(const short8*)&As[(ar * 8 + (au ^ (lrow & 7))) * 8];
            }
#pragma unroll
            for (int n = 0; n < NF; n++) {
                int br = wc * NF * 16 + n * 16 + lrow;
                int au = kk / 8 + lkg;
                bfr[n] = *(const short8*)&Bs[(br * 8 + (au ^ (lrow & 7))) * 8];
            }
#pragma unroll
            for (int m = 0; m < MF; m++)
#pragma unroll
                for (int n = 0; n < NF; n++)
                    acc[m][n] = __builtin_amdgcn_mfma_f32_16x16x32_bf16(
                        af[m], bfr[n], acc[m][n], 0, 0, 0);
        }
        __syncthreads();
    }
    // C store
#pragma unroll
    for (int m = 0; m < MF; m++)
#pragma unroll
        for (int n = 0; n < NF; n++)
#pragma unroll
            for (int r = 0; r < 4; r++) {
                int gr = row0 + wr * MF * 16 + m * 16 + lkg * 4 + r;
                int gc = col0 + wc * NF * 16 + n * 16 + lrow;
                if (gr < M) {
                    if (OUT_BF16)
                        ((unsigned short*)C)[(size_t)gr * NC + gc] = f2bf(acc[m][n][r]);
                    else
                        ((float*)C)[(size_t)gr * NC + gc] = acc[m][n][r];
                }
            }
    // fused attention scores from f32 accumulators
    if (SC_MODE) {
        float asv[NF], adv[NF];
#pragma unroll
        for (int n = 0; n < NF; n++) {
            int gc = col0 + wc * NF * 16 + n * 16 + lrow;
            asv[n] = avs[gc];
            adv[n] = avd[gc];
        }
#pragma unroll
        for (int m = 0; m < MF; m++)
#pragma unroll
            for (int r = 0; r < 4; r++) {
                float ps = 0.f, pd = 0.f;
#pragma unroll
                for (int n = 0; n < NF; n++) {
                    ps += acc[m][n][r] * asv[n];
                    pd += acc[m][n][r] * adv[n];
                }
#pragma unroll
                for (int o = 1; o < 16; o <<= 1) {
                    ps += __shfl_xor(ps, o, 64);
                    pd += __shfl_xor(pd, o, 64);
                }
                if (lrow == 0) {
                    int lr = wr * MF * 16 + m * 16 + lkg * 4 + r;
                    ps_lds[wc][lr] = ps;
                    pd_lds[wc][lr] = pd;
                }
            }
        __syncthreads();
        for (int rr = tid; rr < BM; rr += 256) {
            int gr = row0 + rr;
            if (gr < M) {
                float s = 0.f, d = 0.f;
#pragma unroll
                for (int w = 0; w < WN; w++) {
                    s += ps_lds[w][rr];
                    d += pd_lds[w][rr];
                }
                if (SC_MODE == 1) {
                    s_src[(size_t)gr * H1 + blockIdx.y] = s;
                    s_dst[(size_t)gr * H1 + blockIdx.y] = d;
                } else {
                    s_src[gr] = s;
                    s_dst[gr] = d;
                }
            }
        }
    }
}

// --------------------------- conv1 aggregate: wave per node -----------------
// Softmax layout: lane = (edge jj=lane>>2, head h4=lane&3); 16 edges/chunk.
// Gather: lane owns channels [8l,8l+8), head hg=lane>>4. Per chunk, alpha+src
// are computed once in softmax layout and shfl'd into the gather; rows decode
// via dword lo/hi; 4x unrolled for memory-level parallelism.
__global__ __launch_bounds__(256) void k_agg1(
    const unsigned short* __restrict__ h1b, const float* __restrict__ s_src,
    const float* __restrict__ s_dst, const int* __restrict__ rowstart,
    const int* __restrict__ adj, const float* __restrict__ b1,
    unsigned short* __restrict__ out1, int N) {
    int wv = (blockIdx.x * blockDim.x + threadIdx.x) >> 6;
    if (wv >= N) return;
    int lane = threadIdx.x & 63;
    int beg = rowstart[wv], end = rowstart[wv + 1];
    int h4 = lane & 3, jj = lane >> 2;
    float sdh = s_dst[(size_t)wv * 4 + h4];
    // max
    float m = -1e30f;
    for (int c0 = beg; c0 < end; c0 += 16) {
        int j = c0 + jj;
        if (j < end) {
            int sj = adj[j];
            float e = LRELU(s_src[(size_t)sj * 4 + h4] + sdh);
            m = fmaxf(m, e);
        }
    }
#pragma unroll
    for (int o = 4; o < 64; o <<= 1) m = fmaxf(m, __shfl_xor(m, o, 64));
    // denom
    float dn = 0.f;
    for (int c0 = beg; c0 < end; c0 += 16) {
        int j = c0 + jj;
        if (j < end) {
            int sj = adj[j];
            float e = LRELU(s_src[(size_t)sj * 4 + h4] + sdh);
            dn += __expf(e - m);
        }
    }
#pragma unroll
    for (int o = 4; o < 64; o <<= 1) dn += __shfl_xor(dn, o, 64);
    float inv = 1.f / (dn + 1e-16f);
    // gather
    int hg = lane >> 4;
    float aL[4] = {}, aH[4] = {};
#define ACC1(vv, aa)                                   \
    do {                                               \
        aL[0] += (aa)*bflo(vv.x); aH[0] += (aa)*bfhi(vv.x); \
        aL[1] += (aa)*bflo(vv.y); aH[1] += (aa)*bfhi(vv.y); \
        aL[2] += (aa)*bflo(vv.z); aH[2] += (aa)*bfhi(vv.z); \
        aL[3] += (aa)*bflo(vv.w); aH[3] += (aa)*bfhi(vv.w); \
    } while (0)
    for (int c0 = beg; c0 < end; c0 += 16) {
        int j = c0 + jj;
        float av = 0.f;
        int sjv = 0;
        if (j < end) {
            sjv = adj[j];
            float e = LRELU(s_src[(size_t)sjv * 4 + h4] + sdh);
            av = __expf(e - m) * inv;
        }
        int cnt = min(16, end - c0);
        int j2 = 0;
        for (; j2 + 4 <= cnt; j2 += 4) {
            int l0 = (j2 + 0) * 4 + hg, l1 = (j2 + 1) * 4 + hg;
            int l2 = (j2 + 2) * 4 + hg, l3 = (j2 + 3) * 4 + hg;
            int s0 = __shfl(sjv, l0, 64), s1 = __shfl(sjv, l1, 64);
            int s2 = __shfl(sjv, l2, 64), s3 = __shfl(sjv, l3, 64);
            float a0 = __shfl(av, l0, 64), a1 = __shfl(av, l1, 64);
            float a2 = __shfl(av, l2, 64), a3 = __shfl(av, l3, 64);
            uint4 v0 = *(const uint4*)&h1b[(size_t)s0 * D1 + lane * 8];
            uint4 v1 = *(const uint4*)&h1b[(size_t)s1 * D1 + lane * 8];
            uint4 v2 = *(const uint4*)&h1b[(size_t)s2 * D1 + lane * 8];
            uint4 v3 = *(const uint4*)&h1b[(size_t)s3 * D1 + lane * 8];
            ACC1(v0, a0); ACC1(v1, a1); ACC1(v2, a2); ACC1(v3, a3);
        }
        for (; j2 < cnt; ++j2) {
            int l0 = j2 * 4 + hg;
            int s0 = __shfl(sjv, l0, 64);
            float a0 = __shfl(av, l0, 64);
            uint4 v0 = *(const uint4*)&h1b[(size_t)s0 * D1 + lane * 8];
            ACC1(v0, a0);
        }
    }
#undef ACC1
    const float4* bp = (const float4*)&b1[lane * 8];
    float4 bb0 = bp[0], bb1 = bp[1];
    float r[8];
    r[0] = aL[0] + bb0.x; r[1] = aH[0] + bb0.y;
    r[2] = aL[1] + bb0.z; r[3] = aH[1] + bb0.w;
    r[4] = aL[2] + bb1.x; r[5] = aH[2] + bb1.y;
    r[6] = aL[3] + bb1.z; r[7] = aH[3] + bb1.w;
    unsigned short o16[8];
#pragma unroll
    for (int i = 0; i < 8; i++) {
        float z = r[i] > 0.f ? r[i] : expm1f(r[i]);
        o16[i] = f2bf(z);
    }
    *(short8*)&out1[(size_t)wv * D1 + lane * 8] = *(const short8*)o16;
}

// --------------------------- conv2 aggregate: wave per node -----------------
// Softmax: lane=edge (64/chunk). Gather: 4 edges x 16 lanes x 4ch (bf16 rows).
__global__ __launch_bounds__(256) void k_agg2(
    const unsigned short* __restrict__ h2lin, const float* __restrict__ s_src,
    const float* __restrict__ s_dst, const int* __restrict__ rowstart,
    const int* __restrict__ adj, const float* __restrict__ b2,
    float* __restrict__ h2, int N) {
    int wv = (blockIdx.x * blockDim.x + threadIdx.x) >> 6;
    if (wv >= N) return;
    int lane = threadIdx.x & 63;
    int beg = rowstart[wv], end = rowstart[wv + 1];
    float sd = s_dst[wv];
    float m = -1e30f;
    for (int c0 = beg; c0 < end; c0 += 64) {
        int j = c0 + lane;
        if (j < end) m = fmaxf(m, LRELU(s_src[adj[j]] + sd));
    }
#pragma unroll
    for (int o = 1; o < 64; o <<= 1) m = fmaxf(m, __shfl_xor(m, o, 64));
    float dn = 0.f;
    for (int c0 = beg; c0 < end; c0 += 64) {
        int j = c0 + lane;
        if (j < end) dn += __expf(LRELU(s_src[adj[j]] + sd) - m);
    }
#pragma unroll
    for (int o = 1; o < 64; o <<= 1) dn += __shfl_xor(dn, o, 64);
    float inv = 1.f / (dn + 1e-16f);
    int eg = lane >> 4, ch = (lane & 15) * 4;
    float a0 = 0.f, a1 = 0.f, a2 = 0.f, a3 = 0.f;
    for (int j0 = beg; j0 < end; j0 += 4) {
        int j = j0 + eg;
        if (j < end) {
            int sj = adj[j];
            float a = __expf(LRELU(s_src[sj] + sd) - m) * inv;
            uint2 rv = *(const uint2*)&h2lin[(size_t)sj * C2 + ch];
            a0 += a * bflo(rv.x); a1 += a * bfhi(rv.x);
            a2 += a * bflo(rv.y); a3 += a * bfhi(rv.y);
        }
    }
#pragma unroll
    for (int o = 16; o < 64; o <<= 1) {
        a0 += __shfl_xor(a0, o, 64);
        a1 += __shfl_xor(a1, o, 64);
        a2 += __shfl_xor(a2, o, 64);
        a3 += __shfl_xor(a3, o, 64);
    }
    if (lane < 16) {
        const float4 bb = *(const float4*)&b2[ch];
        float r0 = a0 + bb.x, r1 = a1 + bb.y, r2 = a2 + bb.z, r3 = a3 + bb.w;
        r0 = r0 > 0.f ? r0 : expm1f(r0);
        r1 = r1 > 0.f ? r1 : expm1f(r1);
        r2 = r2 > 0.f ? r2 : expm1f(r2);
        r3 = r3 > 0.f ? r3 : expm1f(r3);
        *(float4*)&h2[(size_t)wv * C2 + ch] = make_float4(r0, r1, r2, r3);
    }
}

// --------------------------- MLP + LN + out ---------------------------------
__global__ __launch_bounds__(256) void k_mlp(
    const float* __restrict__ h2, const float* __restrict__ Wm1,
    const float* __restrict__ bm1, const float* __restrict__ g_ln,
    const float* __restrict__ b_ln, const float* __restrict__ Wm2,
    const float* __restrict__ bm2, float* __restrict__ out, int N) {
    __shared__ float w1[C2 * DM1];
    __shared__ float w2[DM1 * DM2];
    __shared__ float cb1[DM1], cg[DM1], cbl[DM1], cb2[DM2];
    int tid = threadIdx.x;
    for (int i = tid; i < C2 * DM1; i += 256) w1[i] = Wm1[i];
    for (int i = tid; i < DM1 * DM2; i += 256) w2[i] = Wm2[i];
    if (tid < DM1) {
        cb1[tid] = bm1[tid];
        cg[tid] = g_ln[tid];
        cbl[tid] = b_ln[tid];
    } else if (tid < DM1 + DM2) {
        cb2[tid - DM1] = bm2[tid - DM1];
    }
    __syncthreads();
    int n = blockIdx.x * 256 + tid;
    if (n >= N) return;
    float h[C2];
    const float4* hp = (const float4*)&h2[(size_t)n * C2];
#pragma unroll
    for (int i = 0; i < C2 / 4; i++) {
        float4 v = hp[i];
        h[4 * i] = v.x; h[4 * i + 1] = v.y;
        h[4 * i + 2] = v.z; h[4 * i + 3] = v.w;
    }
    float t[DM1];
#pragma unroll
    for (int j = 0; j < DM1; j++) {
        float a = cb1[j];
#pragma unroll
        for (int c = 0; c < C2; c++) a += h[c] * w1[c * DM1 + j];
        t[j] = a;
    }
    float mu = 0.f;
#pragma unroll
    for (int j = 0; j < DM1; j++) mu += t[j];
    mu *= (1.f / DM1);
    float var = 0.f;
#pragma unroll
    for (int j = 0; j < DM1; j++) {
        float d = t[j] - mu;
        var += d * d;
    }
    var *= (1.f / DM1);
    float rs = rsqrtf(var + 1e-5f);
#pragma unroll
    for (int j = 0; j < DM1; j++) {
        float z = (t[j] - mu) * rs * cg[j] + cbl[j];
        t[j] = z > 0.f ? z : 0.f;
    }
    float o[DM2];
#pragma unroll
    for (int k = 0; k < DM2; k++) {
        float a = cb2[k];
#pragma unroll
        for (int j = 0; j < DM1; j++) a += t[j] * w2[j * DM2 + k];
        o[k] = a;
    }
    float4* op = (float4*)&out[(size_t)n * DM2];
    op[0] = make_float4(o[0], o[1], o[2], o[3]);
    op[1] = make_float4(o[4], o[5], o[6], o[7]);
    op[2] = make_float4(o[8], o[9], o[10], o[11]);
    op[3] = make_float4(o[12], o[13], o[14], o[15]);
}

// ---------------------------------------------------------------------------
extern "C" void kernel_launch(void* const* d_in, const int* in_sizes, int n_in,
                              void* d_out, int out_size, void* d_ws,
                              size_t ws_size, hipStream_t stream) {
    const float* x      = (const float*)d_in[0];
    const void*  ei     = d_in[1];
    const float* W1     = (const float*)d_in[3];
    const float* a_src1 = (const float*)d_in[4];
    const float* a_dst1 = (const float*)d_in[5];
    const float* b1     = (const float*)d_in[6];
    const float* W2     = (const float*)d_in[7];
    const float* a_src2 = (const float*)d_in[8];
    const float* a_dst2 = (const float*)d_in[9];
    const float* b2     = (const float*)d_in[10];
    const float* Wm1    = (const float*)d_in[11];
    const float* bm1    = (const float*)d_in[12];
    const float* g_ln   = (const float*)d_in[13];
    const float* b_ln   = (const float*)d_in[14];
    const float* Wm2    = (const float*)d_in[15];
    const float* bm2    = (const float*)d_in[16];

    const int N    = in_sizes[0] / F_IN;
    const int E    = in_sizes[1] / 2;
    const int Etot = E + N;
    const int nb   = (N + 1023) / 1024;

    char* ws = (char*)d_ws;
    size_t off = 0;
    auto alloc = [&](size_t bytes) {
        size_t o = off;
        off += (bytes + 255) & ~(size_t)255;
        return o;
    };
    int*   flag     = (int*)(ws + alloc(4));
    int*   src32    = (int*)(ws + alloc((size_t)Etot * 4));
    int*   dst32    = (int*)(ws + alloc((size_t)Etot * 4));
    int*   deg      = (int*)(ws + alloc((size_t)N * 4));
    int*   bsum     = (int*)(ws + alloc(4096 * 4));
    int*   boff     = (int*)(ws + alloc(4096 * 4));
    int*   rowstart = (int*)(ws + alloc((size_t)(N + 1) * 4));
    int*   cursor   = (int*)(ws + alloc((size_t)N * 4));
    int*   adj      = (int*)(ws + alloc((size_t)Etot * 4));
    float* s_src1   = (float*)(ws + alloc((size_t)N * H1 * 4));
    float* s_dst1   = (float*)(ws + alloc((size_t)N * H1 * 4));
    unsigned short* xb    = (unsigned short*)(ws + alloc((size_t)N * F_IN * 2));
    unsigned short* W1t   = (unsigned short*)(ws + alloc((size_t)F_IN * D1 * 2));
    unsigned short* W2t   = (unsigned short*)(ws + alloc((size_t)D1 * C2 * 2));
    unsigned short* h1b   = (unsigned short*)(ws + alloc((size_t)N * D1 * 2));
    unsigned short* out1  = (unsigned short*)(ws + alloc((size_t)N * D1 * 2));
    unsigned short* h2lin = (unsigned short*)(ws + alloc((size_t)N * C2 * 2));
    float* h2    = (float*)(ws + alloc((size_t)N * C2 * 4));
    float* s_src2 = s_src1;
    float* s_dst2 = s_dst1;

    hipMemsetAsync(deg, 0, (size_t)N * 4, stream);
    k_detect<<<1, 256, 0, stream>>>(ei, E, flag);
    int n8 = N * F_IN / 8;
    int total_cp = Etot + n8 + F_IN * D1 + D1 * C2;
    k_convert_prep<<<(total_cp + 255) / 256, 256, 0, stream>>>(
        ei, flag, E, N, src32, dst32, deg, x, W1, W2, xb, W1t, W2t, n8);
    k_scan1<<<nb, 256, 0, stream>>>(deg, bsum, N);
    k_scan2<<<1, 1024, 0, stream>>>(bsum, boff, nb);
    k_scan3<<<nb, 256, 0, stream>>>(deg, boff, rowstart, cursor, N, Etot);
    k_fill<<<(Etot + 255) / 256, 256, 0, stream>>>(src32, dst32, cursor, adj, Etot);

    // conv1: h1 = x@W1 (scores fused: block col-range == one head)
    k_gemm_bf16<2, 2, 4, 4, true, 1>
        <<<dim3((N + 127) / 128, D1 / 128), 256, 0, stream>>>(
            xb, W1t, h1b, N, F_IN, D1, a_src1, a_dst1, s_src1, s_dst1);
    k_agg1<<<(N * 64 + 255) / 256, 256, 0, stream>>>(h1b, s_src1, s_dst1, rowstart,
                                                     adj, b1, out1, N);

    // conv2: h2lin = out1@W2 (bf16 out; scores fused: block col-range == C2)
    k_gemm_bf16<4, 1, 2, 4, true, 2>
        <<<dim3((N + 127) / 128, 1), 256, 0, stream>>>(
            out1, W2t, h2lin, N, D1, C2, a_src2, a_dst2, s_src2, s_dst2);
    k_agg2<<<(N * 64 + 255) / 256, 256, 0, stream>>>(h2lin, s_src2, s_dst2, rowstart,
                                                     adj, b2, h2, N);

    // MLP head
    k_mlp<<<(N + 255) / 256, 256, 0, stream>>>(h2, Wm1, bm1, g_ln, b_ln, Wm2, bm2,
                                               (float*)d_out, N);
}

// Round 10
// 322.045 us; speedup vs baseline: 2.3236x; 1.0585x over previous
//
#include <hip/hip_runtime.h>
#include <cmath>

// ---------------------------------------------------------------------------
// SpectralGAT: 2-layer GAT (H1=4,C1=128 concat -> 512; H=1,C2=64) + MLP.
// bf16 MFMA GEMMs (global_load_lds staging, both-sides swizzle); scores fused
// into GEMM epilogues; wave-per-node aggregation with online softmax, chunk-0
// register stash and LDS alpha staging; rank-based CSR fill. Rebuilt per call.
// ---------------------------------------------------------------------------

#define F_IN 128
#define H1   4
#define C1   128
#define D1   512   // H1*C1
#define C2   64
#define DM1  32
#define DM2  16

#define LRELU(x) ((x) > 0.f ? (x) : 0.2f * (x))

typedef float f32x4 __attribute__((ext_vector_type(4)));
typedef short short8 __attribute__((ext_vector_type(8)));

static __device__ __forceinline__ float bf2f(unsigned short u) {
    return __builtin_bit_cast(float, (unsigned)u << 16);
}
static __device__ __forceinline__ unsigned short f2bf(float f) {
    unsigned u = __builtin_bit_cast(unsigned, f);
    u = (u + 0x7fffu + ((u >> 16) & 1u)) >> 16;
    return (unsigned short)u;
}
static __device__ __forceinline__ float bflo(unsigned d) {
    return __builtin_bit_cast(float, d << 16);
}
static __device__ __forceinline__ float bfhi(unsigned d) {
    return __builtin_bit_cast(float, d & 0xffff0000u);
}

// --------------------------- edge dtype detect ------------------------------
__global__ void k_detect(const void* ei, int E, int* flag) {
    __shared__ int any;
    if (threadIdx.x == 0) any = 0;
    __syncthreads();
    const int* p = (const int*)ei;
    int cnt = E < 4096 ? E : 4096;
    int stride = E / cnt;
    int local = 0;
    for (int i = threadIdx.x; i < cnt; i += blockDim.x) {
        long long idx = (long long)i * stride;
        local |= p[2 * idx + 1];
    }
    if (local) atomicOr(&any, 1);
    __syncthreads();
    if (threadIdx.x == 0) *flag = (any == 0) ? 1 : 0;
}

// fused: edge convert (+self-loops, degree count, per-edge rank) AND bf16 prep
__global__ void k_convert_prep(const void* ei, const int* flag, int E, int N,
                               int* src32, int* dst32, int* deg, int* rank32,
                               const float* __restrict__ x,
                               const float* __restrict__ W1,
                               const float* __restrict__ W2,
                               unsigned short* __restrict__ xb,
                               unsigned short* __restrict__ W1t,
                               unsigned short* __restrict__ W2t, int n8) {
    int i = blockIdx.x * blockDim.x + threadIdx.x;
    int Etot = E + N;
    if (i < Etot) {
        int s, d;
        if (i < E) {
            if (*flag) {
                const long long* q = (const long long*)ei;
                s = (int)q[i];
                d = (int)q[(size_t)E + i];
            } else {
                const int* q = (const int*)ei;
                s = q[i];
                d = q[(size_t)E + i];
            }
        } else {
            s = i - E;
            d = i - E;
        }
        src32[i] = s;
        dst32[i] = d;
        rank32[i] = atomicAdd(&deg[d], 1);
        return;
    }
    int i1 = i - Etot;
    if (i1 < n8) {
        const float4* p = (const float4*)(x + (size_t)i1 * 8);
        float4 a = p[0], b = p[1];
        unsigned short r[8] = {f2bf(a.x), f2bf(a.y), f2bf(a.z), f2bf(a.w),
                               f2bf(b.x), f2bf(b.y), f2bf(b.z), f2bf(b.w)};
        *(short8*)(xb + (size_t)i1 * 8) = *(const short8*)r;
        return;
    }
    int i2 = i1 - n8;
    if (i2 < F_IN * D1) {  // W1t[n*F_IN+k] = W1[k*D1+n]
        int nn = i2 / F_IN, kk = i2 - nn * F_IN;
        W1t[i2] = f2bf(W1[(size_t)kk * D1 + nn]);
        return;
    }
    int i3 = i2 - F_IN * D1;
    if (i3 < D1 * C2) {  // W2t[n*D1+k] = W2[k*C2+n]
        int nn = i3 / D1, kk = i3 - nn * D1;
        W2t[i3] = f2bf(W2[(size_t)kk * C2 + nn]);
    }
}

// --------------------------- parallel scan (3 phases) -----------------------
__global__ __launch_bounds__(256) void k_scan1(const int* __restrict__ deg,
                                               int* __restrict__ bsum, int N) {
    int t = threadIdx.x;
    int base = blockIdx.x * 1024 + t * 4;
    int s = 0;
    if (base + 3 < N) {
        int4 v = *(const int4*)&deg[base];
        s = v.x + v.y + v.z + v.w;
    } else {
        for (int k = 0; k < 4; k++)
            if (base + k < N) s += deg[base + k];
    }
#pragma unroll
    for (int o = 1; o < 64; o <<= 1) s += __shfl_xor(s, o, 64);
    __shared__ int ws[4];
    if ((t & 63) == 0) ws[t >> 6] = s;
    __syncthreads();
    if (t == 0) bsum[blockIdx.x] = ws[0] + ws[1] + ws[2] + ws[3];
}

__global__ __launch_bounds__(1024) void k_scan2(const int* __restrict__ bsum,
                                                int* __restrict__ boff, int nb) {
    __shared__ int wsum[16];
    __shared__ int woff[16];
    int t = threadIdx.x, lane = t & 63, wid = t >> 6;
    int v = (t < nb) ? bsum[t] : 0;
    int x = v;
#pragma unroll
    for (int o = 1; o < 64; o <<= 1) {
        int tv = __shfl_up(x, o, 64);
        if (lane >= o) x += tv;
    }
    if (lane == 63) wsum[wid] = x;
    __syncthreads();
    if (wid == 0) {
        int y = (lane < 16) ? wsum[lane] : 0;
        int z = y;
#pragma unroll
        for (int o = 1; o < 16; o <<= 1) {
            int tv = __shfl_up(z, o, 64);
            if (lane >= o) z += tv;
        }
        if (lane < 16) woff[lane] = z - y;
    }
    __syncthreads();
    if (t < nb) boff[t] = woff[wid] + x - v;
}

__global__ __launch_bounds__(256) void k_scan3(const int* __restrict__ deg,
                                               const int* __restrict__ boff,
                                               int* __restrict__ rowstart, int N,
                                               int Etot) {
    int t = threadIdx.x, lane = t & 63, wid = t >> 6;
    int base = blockIdx.x * 1024 + t * 4;
    int v0 = 0, v1 = 0, v2 = 0, v3 = 0;
    if (base + 3 < N) {
        int4 v = *(const int4*)&deg[base];
        v0 = v.x; v1 = v.y; v2 = v.z; v3 = v.w;
    } else {
        if (base + 0 < N) v0 = deg[base + 0];
        if (base + 1 < N) v1 = deg[base + 1];
        if (base + 2 < N) v2 = deg[base + 2];
        if (base + 3 < N) v3 = deg[base + 3];
    }
    int s4 = v0 + v1 + v2 + v3;
    int x = s4;
#pragma unroll
    for (int o = 1; o < 64; o <<= 1) {
        int tv = __shfl_up(x, o, 64);
        if (lane >= o) x += tv;
    }
    __shared__ int ws[4];
    if (lane == 63) ws[wid] = x;
    __syncthreads();
    int woff = 0;
#pragma unroll
    for (int w = 0; w < 4; w++)
        if (w < wid) woff += ws[w];
    int ex = boff[blockIdx.x] + woff + (x - s4);
    int e0 = ex, e1 = ex + v0, e2 = e1 + v1, e3 = e2 + v2;
    if (base + 0 < N) rowstart[base + 0] = e0;
    if (base + 1 < N) rowstart[base + 1] = e1;
    if (base + 2 < N) rowstart[base + 2] = e2;
    if (base + 3 < N) rowstart[base + 3] = e3;
    if (blockIdx.x == 0 && t == 0) rowstart[N] = Etot;
}

// rank-based fill: no atomics
__global__ void k_fill(const int* __restrict__ src32, const int* __restrict__ dst32,
                       const int* __restrict__ rank32,
                       const int* __restrict__ rowstart, int* __restrict__ adj,
                       int Etot) {
    int i = blockIdx.x * blockDim.x + threadIdx.x;
    if (i < Etot) adj[rowstart[dst32[i]] + rank32[i]] = src32[i];
}

// --------------------------- bf16 MFMA GEMM (+fused scores) -----------------
// C[M,NC] = A[M,K] @ Bt[NC,K]^T.  K % 64 == 0.  256 threads = 4 waves.
// Staging: global_load_lds width=16, linear LDS dest, source pre-swizzled so
// ds_read applies unit ^= (row&7)  (rule-21 both-sides swizzle).
// SC_MODE: 0=none, 1=per-head scores (s[gr*H1+blockIdx.y], a-vec flat[gc]),
//          2=full-row scores (s[gr]).
template <int WM, int WN, int MF, int NF, bool OUT_BF16, int SC_MODE>
__global__ __launch_bounds__(256) void k_gemm_bf16(
    const unsigned short* __restrict__ A, const unsigned short* __restrict__ Bt,
    void* __restrict__ C, int M, int K, int NC,
    const float* __restrict__ avs, const float* __restrict__ avd,
    float* __restrict__ s_src, float* __restrict__ s_dst) {
    constexpr int BM = WM * MF * 16;
    constexpr int BN = WN * NF * 16;
    constexpr int BK = 64;  // 8 units of 16B per row
    __shared__ unsigned short As[BM * BK];
    __shared__ unsigned short Bs[BN * BK];
    __shared__ float ps_lds[WN][BM], pd_lds[WN][BM];
    const int tid = threadIdx.x;
    const int row0 = blockIdx.x * BM, col0 = blockIdx.y * BN;
    const int wave = tid >> 6, lane = tid & 63;
    const int wr = wave / WN, wc = wave % WN;
    const int lrow = lane & 15, lkg = lane >> 4;
    f32x4 acc[MF][NF] = {};
    for (int k0 = 0; k0 < K; k0 += BK) {
#pragma unroll
        for (int inst = 0; inst < (BM * 8) / 256; ++inst) {
            int ibase = inst * 256 + wave * 64;
            int i = ibase + lane;
            int r = i >> 3, u = i & 7, su = u ^ (r & 7);
            const unsigned short* gp = A + (size_t)(row0 + r) * K + k0 + su * 8;
            __builtin_amdgcn_global_load_lds(
                (const __attribute__((address_space(1))) void*)gp,
                (__attribute__((address_space(3))) void*)&As[ibase * 8], 16, 0, 0);
        }
#pragma unroll
        for (int inst = 0; inst < (BN * 8) / 256; ++inst) {
            int ibase = inst * 256 + wave * 64;
            int i = ibase + lane;
            int r = i >> 3, u = i & 7, su = u ^ (r & 7);
            const unsigned short* gp = Bt + (size_t)(col0 + r) * K + k0 + su * 8;
            __builtin_amdgcn_global_load_lds(
                (const __attribute__((address_space(1))) void*)gp,
                (__attribute__((address_space(3))) void*)&Bs[ibase * 8], 16, 0, 0);
        }
        __syncthreads();
#pragma unroll
        for (int kk = 0; kk < BK; kk += 32) {
            short8 af[MF], bfr[NF];
#pragma unroll
            for (int m = 0; m < MF; m++) {
                int ar = wr * MF * 16 + m * 16 + lrow;
                int au = kk / 8 + lkg;
                af[m] = *(const short8*)&As[(ar * 8 + (au ^ (lrow & 7))) * 8];
            }
#pragma unroll
            for (int n = 0; n < NF; n++) {
                int br = wc * NF * 16 + n * 16 + lrow;
                int au = kk / 8 + lkg;
                bfr[n] = *(const short8*)&Bs[(br * 8 + (au ^ (lrow & 7))) * 8];
            }
#pragma unroll
            for (int m = 0; m < MF; m++)
#pragma unroll
                for (int n = 0; n < NF; n++)
                    acc[m][n] = __builtin_amdgcn_mfma_f32_16x16x32_bf16(
                        af[m], bfr[n], acc[m][n], 0, 0, 0);
        }
        __syncthreads();
    }
    // C store
#pragma unroll
    for (int m = 0; m < MF; m++)
#pragma unroll
        for (int n = 0; n < NF; n++)
#pragma unroll
            for (int r = 0; r < 4; r++) {
                int gr = row0 + wr * MF * 16 + m * 16 + lkg * 4 + r;
                int gc = col0 + wc * NF * 16 + n * 16 + lrow;
                if (gr < M) {
                    if (OUT_BF16)
                        ((unsigned short*)C)[(size_t)gr * NC + gc] = f2bf(acc[m][n][r]);
                    else
                        ((float*)C)[(size_t)gr * NC + gc] = acc[m][n][r];
                }
            }
    // fused attention scores from f32 accumulators
    if (SC_MODE) {
        float asv[NF], adv[NF];
#pragma unroll
        for (int n = 0; n < NF; n++) {
            int gc = col0 + wc * NF * 16 + n * 16 + lrow;
            asv[n] = avs[gc];
            adv[n] = avd[gc];
        }
#pragma unroll
        for (int m = 0; m < MF; m++)
#pragma unroll
            for (int r = 0; r < 4; r++) {
                float ps = 0.f, pd = 0.f;
#pragma unroll
                for (int n = 0; n < NF; n++) {
                    ps += acc[m][n][r] * asv[n];
                    pd += acc[m][n][r] * adv[n];
                }
#pragma unroll
                for (int o = 1; o < 16; o <<= 1) {
                    ps += __shfl_xor(ps, o, 64);
                    pd += __shfl_xor(pd, o, 64);
                }
                if (lrow == 0) {
                    int lr = wr * MF * 16 + m * 16 + lkg * 4 + r;
                    ps_lds[wc][lr] = ps;
                    pd_lds[wc][lr] = pd;
                }
            }
        __syncthreads();
        for (int rr = tid; rr < BM; rr += 256) {
            int gr = row0 + rr;
            if (gr < M) {
                float s = 0.f, d = 0.f;
#pragma unroll
                for (int w = 0; w < WN; w++) {
                    s += ps_lds[w][rr];
                    d += pd_lds[w][rr];
                }
                if (SC_MODE == 1) {
                    s_src[(size_t)gr * H1 + blockIdx.y] = s;
                    s_dst[(size_t)gr * H1 + blockIdx.y] = d;
                } else {
                    s_src[gr] = s;
                    s_dst[gr] = d;
                }
            }
        }
    }
}

// --------------------------- conv1 aggregate: wave per node -----------------
// Online softmax (fused max+denom), chunk-0 scalar stash (registers, covers
// deg<=16 ~ 99% of nodes), LDS alpha staging (wave-synchronous lgkmcnt(0)).
__global__ __launch_bounds__(256) void k_agg1(
    const unsigned short* __restrict__ h1b, const float* __restrict__ s_src,
    const float* __restrict__ s_dst, const int* __restrict__ rowstart,
    const int* __restrict__ adj, const float* __restrict__ b1,
    unsigned short* __restrict__ out1, int N) {
    __shared__ uint2 ex_lds[4][64];
    int wv = (blockIdx.x * blockDim.x + threadIdx.x) >> 6;
    if (wv >= N) return;
    int wv4 = (threadIdx.x >> 6) & 3;
    int lane = threadIdx.x & 63;
    int beg = rowstart[wv], end = rowstart[wv + 1];
    int h4 = lane & 3, jj = lane >> 2;
    float sdh = s_dst[(size_t)wv * 4 + h4];
    int nch = (end - beg + 15) >> 4;
    // pass 1: online (m, dn); stash chunk 0 in scalars
    float e0st = -1e30f;
    int s0st = 0;
    float m = -1e30f, dn = 0.f;
    for (int c = 0; c < nch; ++c) {
        int j = beg + c * 16 + jj;
        float e = -1e30f;
        int sj = 0;
        if (j < end) {
            sj = adj[j];
            e = LRELU(s_src[(size_t)sj * 4 + h4] + sdh);
        }
        if (c == 0) { e0st = e; s0st = sj; }
        float nm = fmaxf(m, e);
        dn = dn * __expf(m - nm) + ((j < end) ? __expf(e - nm) : 0.f);
        m = nm;
    }
#pragma unroll
    for (int o = 4; o < 64; o <<= 1) {
        float om = __shfl_xor(m, o, 64);
        float od = __shfl_xor(dn, o, 64);
        float nm = fmaxf(m, om);
        dn = dn * __expf(m - nm) + od * __expf(om - nm);
        m = nm;
    }
    float inv = 1.f / (dn + 1e-16f);
    // pass 2 + gather, chunk by chunk
    int hg = lane >> 4;
    float aL[4] = {}, aH[4] = {};
#define ACC1(vv, aa)                                        \
    do {                                                    \
        aL[0] += (aa)*bflo(vv.x); aH[0] += (aa)*bfhi(vv.x); \
        aL[1] += (aa)*bflo(vv.y); aH[1] += (aa)*bfhi(vv.y); \
        aL[2] += (aa)*bflo(vv.z); aH[2] += (aa)*bfhi(vv.z); \
        aL[3] += (aa)*bflo(vv.w); aH[3] += (aa)*bfhi(vv.w); \
    } while (0)
    for (int c = 0; c < nch; ++c) {
        int j = beg + c * 16 + jj;
        float e;
        int sj;
        if (c == 0) {
            e = e0st;
            sj = s0st;
        } else {
            sj = 0;
            e = -1e30f;
            if (j < end) {
                sj = adj[j];
                e = LRELU(s_src[(size_t)sj * 4 + h4] + sdh);
            }
        }
        float av = (j < end) ? __expf(e - m) * inv : 0.f;
        ex_lds[wv4][lane] = make_uint2((unsigned)sj, __builtin_bit_cast(unsigned, av));
        asm volatile("s_waitcnt lgkmcnt(0)" ::: "memory");
        int cnt = min(16, end - beg - c * 16);
        int j2 = 0;
        for (; j2 + 4 <= cnt; j2 += 4) {
            uint2 e0 = ex_lds[wv4][(j2 + 0) * 4 + hg];
            uint2 e1 = ex_lds[wv4][(j2 + 1) * 4 + hg];
            uint2 e2 = ex_lds[wv4][(j2 + 2) * 4 + hg];
            uint2 e3 = ex_lds[wv4][(j2 + 3) * 4 + hg];
            uint4 v0 = *(const uint4*)&h1b[(size_t)e0.x * D1 + lane * 8];
            uint4 v1 = *(const uint4*)&h1b[(size_t)e1.x * D1 + lane * 8];
            uint4 v2 = *(const uint4*)&h1b[(size_t)e2.x * D1 + lane * 8];
            uint4 v3 = *(const uint4*)&h1b[(size_t)e3.x * D1 + lane * 8];
            float a0 = __builtin_bit_cast(float, e0.y);
            float a1 = __builtin_bit_cast(float, e1.y);
            float a2 = __builtin_bit_cast(float, e2.y);
            float a3 = __builtin_bit_cast(float, e3.y);
            ACC1(v0, a0); ACC1(v1, a1); ACC1(v2, a2); ACC1(v3, a3);
        }
        for (; j2 < cnt; ++j2) {
            uint2 e0 = ex_lds[wv4][j2 * 4 + hg];
            uint4 v0 = *(const uint4*)&h1b[(size_t)e0.x * D1 + lane * 8];
            float a0 = __builtin_bit_cast(float, e0.y);
            ACC1(v0, a0);
        }
    }
#undef ACC1
    const float4* bp = (const float4*)&b1[lane * 8];
    float4 bb0 = bp[0], bb1 = bp[1];
    float r[8];
    r[0] = aL[0] + bb0.x; r[1] = aH[0] + bb0.y;
    r[2] = aL[1] + bb0.z; r[3] = aH[1] + bb0.w;
    r[4] = aL[2] + bb1.x; r[5] = aH[2] + bb1.y;
    r[6] = aL[3] + bb1.z; r[7] = aH[3] + bb1.w;
    unsigned short o16[8];
#pragma unroll
    for (int i = 0; i < 8; i++) {
        float z = r[i] > 0.f ? r[i] : expm1f(r[i]);
        o16[i] = f2bf(z);
    }
    *(short8*)&out1[(size_t)wv * D1 + lane * 8] = *(const short8*)o16;
}

// --------------------------- conv2 aggregate: wave per node -----------------
__global__ __launch_bounds__(256) void k_agg2(
    const unsigned short* __restrict__ h2lin, const float* __restrict__ s_src,
    const float* __restrict__ s_dst, const int* __restrict__ rowstart,
    const int* __restrict__ adj, const float* __restrict__ b2,
    float* __restrict__ h2, int N) {
    int wv = (blockIdx.x * blockDim.x + threadIdx.x) >> 6;
    if (wv >= N) return;
    int lane = threadIdx.x & 63;
    int beg = rowstart[wv], end = rowstart[wv + 1];
    float sd = s_dst[wv];
    float m = -1e30f, dn = 0.f;
    for (int c0 = beg; c0 < end; c0 += 64) {
        int j = c0 + lane;
        float e = -1e30f;
        if (j < end) e = LRELU(s_src[adj[j]] + sd);
        float nm = fmaxf(m, e);
        dn = dn * __expf(m - nm) + ((j < end) ? __expf(e - nm) : 0.f);
        m = nm;
    }
#pragma unroll
    for (int o = 1; o < 64; o <<= 1) {
        float om = __shfl_xor(m, o, 64);
        float od = __shfl_xor(dn, o, 64);
        float nm = fmaxf(m, om);
        dn = dn * __expf(m - nm) + od * __expf(om - nm);
        m = nm;
    }
    float inv = 1.f / (dn + 1e-16f);
    int eg = lane >> 4, ch = (lane & 15) * 4;
    float a0 = 0.f, a1 = 0.f, a2 = 0.f, a3 = 0.f;
    for (int j0 = beg; j0 < end; j0 += 4) {
        int j = j0 + eg;
        if (j < end) {
            int sj = adj[j];
            float a = __expf(LRELU(s_src[sj] + sd) - m) * inv;
            uint2 rv = *(const uint2*)&h2lin[(size_t)sj * C2 + ch];
            a0 += a * bflo(rv.x); a1 += a * bfhi(rv.x);
            a2 += a * bflo(rv.y); a3 += a * bfhi(rv.y);
        }
    }
#pragma unroll
    for (int o = 16; o < 64; o <<= 1) {
        a0 += __shfl_xor(a0, o, 64);
        a1 += __shfl_xor(a1, o, 64);
        a2 += __shfl_xor(a2, o, 64);
        a3 += __shfl_xor(a3, o, 64);
    }
    if (lane < 16) {
        const float4 bb = *(const float4*)&b2[ch];
        float r0 = a0 + bb.x, r1 = a1 + bb.y, r2 = a2 + bb.z, r3 = a3 + bb.w;
        r0 = r0 > 0.f ? r0 : expm1f(r0);
        r1 = r1 > 0.f ? r1 : expm1f(r1);
        r2 = r2 > 0.f ? r2 : expm1f(r2);
        r3 = r3 > 0.f ? r3 : expm1f(r3);
        *(float4*)&h2[(size_t)wv * C2 + ch] = make_float4(r0, r1, r2, r3);
    }
}

// --------------------------- MLP + LN + out ---------------------------------
__global__ __launch_bounds__(256) void k_mlp(
    const float* __restrict__ h2, const float* __restrict__ Wm1,
    const float* __restrict__ bm1, const float* __restrict__ g_ln,
    const float* __restrict__ b_ln, const float* __restrict__ Wm2,
    const float* __restrict__ bm2, float* __restrict__ out, int N) {
    __shared__ float w1[C2 * DM1];
    __shared__ float w2[DM1 * DM2];
    __shared__ float cb1[DM1], cg[DM1], cbl[DM1], cb2[DM2];
    int tid = threadIdx.x;
    for (int i = tid; i < C2 * DM1; i += 256) w1[i] = Wm1[i];
    for (int i = tid; i < DM1 * DM2; i += 256) w2[i] = Wm2[i];
    if (tid < DM1) {
        cb1[tid] = bm1[tid];
        cg[tid] = g_ln[tid];
        cbl[tid] = b_ln[tid];
    } else if (tid < DM1 + DM2) {
        cb2[tid - DM1] = bm2[tid - DM1];
    }
    __syncthreads();
    int n = blockIdx.x * 256 + tid;
    if (n >= N) return;
    float h[C2];
    const float4* hp = (const float4*)&h2[(size_t)n * C2];
#pragma unroll
    for (int i = 0; i < C2 / 4; i++) {
        float4 v = hp[i];
        h[4 * i] = v.x; h[4 * i + 1] = v.y;
        h[4 * i + 2] = v.z; h[4 * i + 3] = v.w;
    }
    float t[DM1];
#pragma unroll
    for (int j = 0; j < DM1; j++) {
        float a = cb1[j];
#pragma unroll
        for (int c = 0; c < C2; c++) a += h[c] * w1[c * DM1 + j];
        t[j] = a;
    }
    float mu = 0.f;
#pragma unroll
    for (int j = 0; j < DM1; j++) mu += t[j];
    mu *= (1.f / DM1);
    float var = 0.f;
#pragma unroll
    for (int j = 0; j < DM1; j++) {
        float d = t[j] - mu;
        var += d * d;
    }
    var *= (1.f / DM1);
    float rs = rsqrtf(var + 1e-5f);
#pragma unroll
    for (int j = 0; j < DM1; j++) {
        float z = (t[j] - mu) * rs * cg[j] + cbl[j];
        t[j] = z > 0.f ? z : 0.f;
    }
    float o[DM2];
#pragma unroll
    for (int k = 0; k < DM2; k++) {
        float a = cb2[k];
#pragma unroll
        for (int j = 0; j < DM1; j++) a += t[j] * w2[j * DM2 + k];
        o[k] = a;
    }
    float4* op = (float4*)&out[(size_t)n * DM2];
    op[0] = make_float4(o[0], o[1], o[2], o[3]);
    op[1] = make_float4(o[4], o[5], o[6], o[7]);
    op[2] = make_float4(o[8], o[9], o[10], o[11]);
    op[3] = make_float4(o[12], o[13], o[14], o[15]);
}

// ---------------------------------------------------------------------------
extern "C" void kernel_launch(void* const* d_in, const int* in_sizes, int n_in,
                              void* d_out, int out_size, void* d_ws,
                              size_t ws_size, hipStream_t stream) {
    const float* x      = (const float*)d_in[0];
    const void*  ei     = d_in[1];
    const float* W1     = (const float*)d_in[3];
    const float* a_src1 = (const float*)d_in[4];
    const float* a_dst1 = (const float*)d_in[5];
    const float* b1     = (const float*)d_in[6];
    const float* W2     = (const float*)d_in[7];
    const float* a_src2 = (const float*)d_in[8];
    const float* a_dst2 = (const float*)d_in[9];
    const float* b2     = (const float*)d_in[10];
    const float* Wm1    = (const float*)d_in[11];
    const float* bm1    = (const float*)d_in[12];
    const float* g_ln   = (const float*)d_in[13];
    const float* b_ln   = (const float*)d_in[14];
    const float* Wm2    = (const float*)d_in[15];
    const float* bm2    = (const float*)d_in[16];

    const int N    = in_sizes[0] / F_IN;
    const int E    = in_sizes[1] / 2;
    const int Etot = E + N;
    const int nb   = (N + 1023) / 1024;

    char* ws = (char*)d_ws;
    size_t off = 0;
    auto alloc = [&](size_t bytes) {
        size_t o = off;
        off += (bytes + 255) & ~(size_t)255;
        return o;
    };
    int*   flag     = (int*)(ws + alloc(4));
    int*   src32    = (int*)(ws + alloc((size_t)Etot * 4));
    int*   dst32    = (int*)(ws + alloc((size_t)Etot * 4));
    int*   rank32   = (int*)(ws + alloc((size_t)Etot * 4));
    int*   deg      = (int*)(ws + alloc((size_t)N * 4));
    int*   bsum     = (int*)(ws + alloc(4096 * 4));
    int*   boff     = (int*)(ws + alloc(4096 * 4));
    int*   rowstart = (int*)(ws + alloc((size_t)(N + 1) * 4));
    int*   adj      = (int*)(ws + alloc((size_t)Etot * 4));
    float* s_src1   = (float*)(ws + alloc((size_t)N * H1 * 4));
    float* s_dst1   = (float*)(ws + alloc((size_t)N * H1 * 4));
    unsigned short* xb    = (unsigned short*)(ws + alloc((size_t)N * F_IN * 2));
    unsigned short* W1t   = (unsigned short*)(ws + alloc((size_t)F_IN * D1 * 2));
    unsigned short* W2t   = (unsigned short*)(ws + alloc((size_t)D1 * C2 * 2));
    unsigned short* h1b   = (unsigned short*)(ws + alloc((size_t)N * D1 * 2));
    unsigned short* out1  = (unsigned short*)(ws + alloc((size_t)N * D1 * 2));
    unsigned short* h2lin = (unsigned short*)(ws + alloc((size_t)N * C2 * 2));
    float* h2    = (float*)(ws + alloc((size_t)N * C2 * 4));
    float* s_src2 = s_src1;
    float* s_dst2 = s_dst1;

    hipMemsetAsync(deg, 0, (size_t)N * 4, stream);
    k_detect<<<1, 256, 0, stream>>>(ei, E, flag);
    int n8 = N * F_IN / 8;
    int total_cp = Etot + n8 + F_IN * D1 + D1 * C2;
    k_convert_prep<<<(total_cp + 255) / 256, 256, 0, stream>>>(
        ei, flag, E, N, src32, dst32, deg, rank32, x, W1, W2, xb, W1t, W2t, n8);
    k_scan1<<<nb, 256, 0, stream>>>(deg, bsum, N);
    k_scan2<<<1, 1024, 0, stream>>>(bsum, boff, nb);
    k_scan3<<<nb, 256, 0, stream>>>(deg, boff, rowstart, N, Etot);
    k_fill<<<(Etot + 255) / 256, 256, 0, stream>>>(src32, dst32, rank32, rowstart,
                                                   adj, Etot);

    // conv1: h1 = x@W1 (scores fused: block col-range == one head)
    k_gemm_bf16<2, 2, 4, 4, true, 1>
        <<<dim3((N + 127) / 128, D1 / 128), 256, 0, stream>>>(
            xb, W1t, h1b, N, F_IN, D1, a_src1, a_dst1, s_src1, s_dst1);
    k_agg1<<<(N * 64 + 255) / 256, 256, 0, stream>>>(h1b, s_src1, s_dst1, rowstart,
                                                     adj, b1, out1, N);

    // conv2: h2lin = out1@W2 (bf16 out; 64x64 tile; scores fused over full C2)
    k_gemm_bf16<2, 2, 2, 2, true, 2>
        <<<dim3((N + 63) / 64, 1), 256, 0, stream>>>(
            out1, W2t, h2lin, N, D1, C2, a_src2, a_dst2, s_src2, s_dst2);
    k_agg2<<<(N * 64 + 255) / 256, 256, 0, stream>>>(h2lin, s_src2, s_dst2, rowstart,
                                                     adj, b2, h2, N);

    // MLP head
    k_mlp<<<(N + 255) / 256, 256, 0, stream>>>(h2, Wm1, bm1, g_ln, b_ln, Wm2, bm2,
                                               (float*)d_out, N);
}